// Round 1
// baseline (908.860 us; speedup 1.0000x reference)
//
#include <hip/hip_runtime.h>

#define N_NODES 100000
#define N_EDGES 25000
#define N_INC   600000
#define D       128
#define NB_E    13   // ceil(25000/2048)
#define NB_N    49   // ceil(100000/2048)

// ---------------- CSR build ----------------

__global__ void count_kernel(const int* __restrict__ node_idx,
                             const int* __restrict__ edge_idx,
                             int* __restrict__ counts_e,
                             int* __restrict__ counts_n) {
    int i = blockIdx.x * blockDim.x + threadIdx.x;
    if (i < N_INC) {
        atomicAdd(&counts_e[edge_idx[i]], 1);
        atomicAdd(&counts_n[node_idx[i]], 1);
    }
}

// K1: per-block sums (2048 elements/block). Blocks [0,NB_E) -> edges, [NB_E, NB_E+NB_N) -> nodes.
__global__ void scan_k1(const int* __restrict__ counts_e,
                        const int* __restrict__ counts_n,
                        int* __restrict__ aux) {
    __shared__ int sdata[256];
    int t = threadIdx.x;
    bool is_edge = blockIdx.x < NB_E;
    const int* in = is_edge ? counts_e : counts_n;
    int n = is_edge ? N_EDGES : N_NODES;
    int blk = is_edge ? blockIdx.x : (blockIdx.x - NB_E);
    int base = blk * 2048 + t * 8;
    int s = 0;
#pragma unroll
    for (int j = 0; j < 8; j++) {
        int idx = base + j;
        if (idx < n) s += in[idx];
    }
    sdata[t] = s;
    __syncthreads();
    for (int off = 128; off > 0; off >>= 1) {
        if (t < off) sdata[t] += sdata[t + off];
        __syncthreads();
    }
    if (t == 0) aux[blockIdx.x] = sdata[0];
}

// K2: one wave scans both aux arrays (exclusive, in place), writes totals.
__global__ void scan_k2(int* __restrict__ aux,
                        int* __restrict__ off_e,
                        int* __restrict__ off_n) {
    int t = threadIdx.x; // 64 threads, one wave
    int v_e = (t < NB_E) ? aux[t] : 0;
    int v_n = (t < NB_N) ? aux[NB_E + t] : 0;
    int se = v_e, sn = v_n;
#pragma unroll
    for (int off = 1; off < 64; off <<= 1) {
        int ae = __shfl_up(se, off);
        if (t >= off) se += ae;
        int an = __shfl_up(sn, off);
        if (t >= off) sn += an;
    }
    if (t < NB_E) aux[t] = se - v_e;           // exclusive
    if (t < NB_N) aux[NB_E + t] = sn - v_n;    // exclusive
    if (t == NB_E - 1) off_e[N_EDGES] = se;    // total = 600000
    if (t == NB_N - 1) off_n[N_NODES] = sn;    // total = 600000
}

// K3: within-block exclusive scan + block offset -> final offsets.
__global__ void scan_k3(const int* __restrict__ counts_e,
                        const int* __restrict__ counts_n,
                        const int* __restrict__ aux,
                        int* __restrict__ off_e,
                        int* __restrict__ off_n) {
    __shared__ int sdata[256];
    int t = threadIdx.x;
    bool is_edge = blockIdx.x < NB_E;
    const int* in = is_edge ? counts_e : counts_n;
    int n = is_edge ? N_EDGES : N_NODES;
    int blk = is_edge ? blockIdx.x : (blockIdx.x - NB_E);
    int* out = is_edge ? off_e : off_n;
    int auxv = aux[blockIdx.x];
    int base = blk * 2048 + t * 8;
    int vals[8];
    int s = 0;
#pragma unroll
    for (int j = 0; j < 8; j++) {
        int idx = base + j;
        vals[j] = (idx < n) ? in[idx] : 0;
        s += vals[j];
    }
    sdata[t] = s;
    __syncthreads();
    // Hillis-Steele inclusive scan over 256 thread sums
    for (int off = 1; off < 256; off <<= 1) {
        int add = (t >= off) ? sdata[t - off] : 0;
        __syncthreads();
        sdata[t] += add;
        __syncthreads();
    }
    int prefix = auxv + sdata[t] - s; // exclusive prefix for this thread's chunk
#pragma unroll
    for (int j = 0; j < 8; j++) {
        int idx = base + j;
        if (idx < n) out[idx] = prefix;
        prefix += vals[j];
    }
}

__global__ void fill_csr(const int* __restrict__ node_idx,
                         const int* __restrict__ edge_idx,
                         const int* __restrict__ off_e,
                         const int* __restrict__ off_n,
                         int* __restrict__ cur_e,
                         int* __restrict__ cur_n,
                         int* __restrict__ csr_e_nodes,
                         int* __restrict__ csr_n_edges) {
    int i = blockIdx.x * blockDim.x + threadIdx.x;
    if (i < N_INC) {
        int e = edge_idx[i];
        int n = node_idx[i];
        int pe = off_e[e] + atomicAdd(&cur_e[e], 1);
        csr_e_nodes[pe] = n;
        int pn = off_n[n] + atomicAdd(&cur_n[n], 1);
        csr_n_edges[pn] = e;
    }
}

// ---------------- GEMM: Y[nrows x 128] = X[nrows x 128] @ W[128 x 128] ----------------

#define WS_STRIDE 132  // pad 128 -> 132: 16B-aligned rows, 4-way (free-ish) bank conflicts

__global__ __launch_bounds__(256) void gemm_kernel(const float* __restrict__ X,
                                                   const float* __restrict__ W,
                                                   float* __restrict__ Y,
                                                   int nrows) {
    __shared__ float Ws[128 * WS_STRIDE]; // Ws[j][k] = W[k][j] (transposed)
    __shared__ float Xs[32 * WS_STRIDE];
    int t = threadIdx.x;

    // load W transposed (coalesced global read)
    for (int i = t; i < 128 * 128; i += 256) {
        int k = i >> 7, j = i & 127;
        Ws[j * WS_STRIDE + k] = W[i];
    }
    // load X tile (32 rows) via float4
    int row0 = blockIdx.x * 32;
    for (int i = t; i < 1024; i += 256) { // 32 rows * 32 float4
        int r = i >> 5;
        int c4 = i & 31;
        int row = row0 + r;
        float4 v = (row < nrows) ? ((const float4*)X)[row * 32 + c4]
                                 : make_float4(0.f, 0.f, 0.f, 0.f);
        float* dst = &Xs[r * WS_STRIDE + c4 * 4];
        dst[0] = v.x; dst[1] = v.y; dst[2] = v.z; dst[3] = v.w;
    }
    __syncthreads();

    int tx = t & 31;  // cols tx + 32*c
    int ty = t >> 5;  // rows ty*4 + r
    float acc[4][4] = {};
    for (int k = 0; k < 128; k += 4) {
        float4 a[4], b[4];
#pragma unroll
        for (int r = 0; r < 4; r++)
            a[r] = *(const float4*)&Xs[(ty * 4 + r) * WS_STRIDE + k];
#pragma unroll
        for (int c = 0; c < 4; c++)
            b[c] = *(const float4*)&Ws[(tx + 32 * c) * WS_STRIDE + k];
#pragma unroll
        for (int r = 0; r < 4; r++)
#pragma unroll
            for (int c = 0; c < 4; c++)
                acc[r][c] += a[r].x * b[c].x + a[r].y * b[c].y +
                             a[r].z * b[c].z + a[r].w * b[c].w;
    }
#pragma unroll
    for (int r = 0; r < 4; r++) {
        int row = row0 + ty * 4 + r;
        if (row < nrows) {
#pragma unroll
            for (int c = 0; c < 4; c++)
                Y[row * D + tx + 32 * c] = acc[r][c];
        }
    }
}

// ---------------- Gather phases ----------------

// e_feat[e][d] = (1/deg_e) * sum_{incidences of e} XW[node][d]
__global__ __launch_bounds__(128) void edge_gather(const float* __restrict__ XW,
                                                   const int* __restrict__ off_e,
                                                   const int* __restrict__ csr_e_nodes,
                                                   float* __restrict__ ef) {
    int e = blockIdx.x;
    int d = threadIdx.x;
    int s = off_e[e], tend = off_e[e + 1];
    float a0 = 0.f, a1 = 0.f, a2 = 0.f, a3 = 0.f;
    int j = s;
    for (; j + 4 <= tend; j += 4) {
        int n0 = csr_e_nodes[j];
        int n1 = csr_e_nodes[j + 1];
        int n2 = csr_e_nodes[j + 2];
        int n3 = csr_e_nodes[j + 3];
        a0 += XW[n0 * D + d];
        a1 += XW[n1 * D + d];
        a2 += XW[n2 * D + d];
        a3 += XW[n3 * D + d];
    }
    for (; j < tend; j++) a0 += XW[csr_e_nodes[j] * D + d];
    float acc = (a0 + a1) + (a2 + a3);
    int cnt = tend - s;
    float binv = (cnt > 0) ? 1.0f / (float)cnt : 0.0f;
    ef[e * D + d] = acc * binv;
}

// out[n][d] = relu?( (1/deg_n) * sum_{edges of n} ef[e][d] + b[d] )
__global__ __launch_bounds__(128) void node_gather(const float* __restrict__ ef,
                                                   const int* __restrict__ off_n,
                                                   const int* __restrict__ csr_n_edges,
                                                   const float* __restrict__ bias,
                                                   float* __restrict__ out,
                                                   int relu) {
    int n = blockIdx.x;
    int d = threadIdx.x;
    int s = off_n[n], tend = off_n[n + 1];
    float a0 = 0.f, a1 = 0.f, a2 = 0.f, a3 = 0.f;
    int j = s;
    for (; j + 4 <= tend; j += 4) {
        int e0 = csr_n_edges[j];
        int e1 = csr_n_edges[j + 1];
        int e2 = csr_n_edges[j + 2];
        int e3 = csr_n_edges[j + 3];
        a0 += ef[e0 * D + d];
        a1 += ef[e1 * D + d];
        a2 += ef[e2 * D + d];
        a3 += ef[e3 * D + d];
    }
    for (; j < tend; j++) a0 += ef[csr_n_edges[j] * D + d];
    float acc = (a0 + a1) + (a2 + a3);
    int cnt = tend - s;
    float dinv = (cnt > 0) ? 1.0f / (float)cnt : 0.0f;
    float v = acc * dinv + bias[d];
    if (relu) v = fmaxf(v, 0.0f);
    out[n * D + d] = v;
}

// ---------------- launch ----------------

extern "C" void kernel_launch(void* const* d_in, const int* in_sizes, int n_in,
                              void* d_out, int out_size, void* d_ws, size_t ws_size,
                              hipStream_t stream) {
    const float* x        = (const float*)d_in[0];
    const int* node_idx   = (const int*)d_in[1];
    const int* edge_idx   = (const int*)d_in[2];
    const float* attr     = (const float*)d_in[3];
    const float* Wl[3]    = {(const float*)d_in[4], (const float*)d_in[6], (const float*)d_in[8]};
    const float* bl[3]    = {(const float*)d_in[5], (const float*)d_in[7], (const float*)d_in[9]};
    float* out = (float*)d_out;

    char* ws = (char*)d_ws;
    float* XW   = (float*)ws;                       // 51,200,000 B
    float* ef   = (float*)(ws + 51200000);          // 12,800,000 B
    int* counts = (int*)(ws + 64000000);            // 250000 ints (counts_e, counts_n, cur_e, cur_n)
    int* counts_e = counts;
    int* counts_n = counts + N_EDGES;
    int* cur_e    = counts + N_EDGES + N_NODES;
    int* cur_n    = counts + 2 * N_EDGES + N_NODES;
    int* off_e  = (int*)(ws + 65000000);            // 25001 ints
    int* off_n  = off_e + (N_EDGES + 1);            // 100001 ints
    int* aux    = off_n + (N_NODES + 1);            // 62 ints
    int* csr_e  = (int*)(ws + 65600000);            // 600000 ints
    int* csr_n  = (int*)(ws + 68000000);            // 600000 ints  (end: 70,400,000 B)

    // zero histogram + cursors (contiguous)
    hipMemsetAsync(counts, 0, (2 * N_EDGES + 2 * N_NODES) * sizeof(int), stream);

    count_kernel<<<(N_INC + 255) / 256, 256, 0, stream>>>(node_idx, edge_idx, counts_e, counts_n);
    scan_k1<<<NB_E + NB_N, 256, 0, stream>>>(counts_e, counts_n, aux);
    scan_k2<<<1, 64, 0, stream>>>(aux, off_e, off_n);
    scan_k3<<<NB_E + NB_N, 256, 0, stream>>>(counts_e, counts_n, aux, off_e, off_n);
    fill_csr<<<(N_INC + 255) / 256, 256, 0, stream>>>(node_idx, edge_idx, off_e, off_n,
                                                      cur_e, cur_n, csr_e, csr_n);

    const float* Xin = x;
    for (int l = 0; l < 3; l++) {
        gemm_kernel<<<(N_NODES + 31) / 32, 256, 0, stream>>>(Xin, Wl[l], XW, N_NODES);
        edge_gather<<<N_EDGES, 128, 0, stream>>>(XW, off_e, csr_e, ef);
        node_gather<<<N_NODES, 128, 0, stream>>>(ef, off_n, csr_n, bl[l], out, (l < 2) ? 1 : 0);
        Xin = out; // h lives in d_out; dead after next layer's GEMM consumes it
    }

    // Output 1: pass-through hyperedge_attr
    hipMemcpyAsync(out + N_NODES * D, attr, N_EDGES * 32 * sizeof(float),
                   hipMemcpyDeviceToDevice, stream);
}

// Round 3
// 637.479 us; speedup vs baseline: 1.4257x; 1.4257x over previous
//
#include <hip/hip_runtime.h>

#define N_NODES 100000
#define N_EDGES 25000
#define N_INC   600000
#define D       128
#define NB_E    13   // ceil(25000/2048)
#define NB_N    49   // ceil(100000/2048)

typedef __bf16 bf16x8 __attribute__((ext_vector_type(8)));
typedef float  f32x4  __attribute__((ext_vector_type(4)));

// ---------------- CSR build ----------------

__global__ void count_kernel(const int* __restrict__ node_idx,
                             const int* __restrict__ edge_idx,
                             int* __restrict__ counts_e,
                             int* __restrict__ counts_n) {
    int i = blockIdx.x * blockDim.x + threadIdx.x;
    if (i < N_INC) {
        atomicAdd(&counts_e[edge_idx[i]], 1);
        atomicAdd(&counts_n[node_idx[i]], 1);
    }
}

__global__ void scan_k1(const int* __restrict__ counts_e,
                        const int* __restrict__ counts_n,
                        int* __restrict__ aux) {
    __shared__ int sdata[256];
    int t = threadIdx.x;
    bool is_edge = blockIdx.x < NB_E;
    const int* in = is_edge ? counts_e : counts_n;
    int n = is_edge ? N_EDGES : N_NODES;
    int blk = is_edge ? blockIdx.x : (blockIdx.x - NB_E);
    int base = blk * 2048 + t * 8;
    int s = 0;
#pragma unroll
    for (int j = 0; j < 8; j++) {
        int idx = base + j;
        if (idx < n) s += in[idx];
    }
    sdata[t] = s;
    __syncthreads();
    for (int off = 128; off > 0; off >>= 1) {
        if (t < off) sdata[t] += sdata[t + off];
        __syncthreads();
    }
    if (t == 0) aux[blockIdx.x] = sdata[0];
}

__global__ void scan_k2(int* __restrict__ aux,
                        int* __restrict__ off_e,
                        int* __restrict__ off_n) {
    int t = threadIdx.x; // 64 threads, one wave
    int v_e = (t < NB_E) ? aux[t] : 0;
    int v_n = (t < NB_N) ? aux[NB_E + t] : 0;
    int se = v_e, sn = v_n;
#pragma unroll
    for (int off = 1; off < 64; off <<= 1) {
        int ae = __shfl_up(se, off);
        if (t >= off) se += ae;
        int an = __shfl_up(sn, off);
        if (t >= off) sn += an;
    }
    if (t < NB_E) aux[t] = se - v_e;
    if (t < NB_N) aux[NB_E + t] = sn - v_n;
    if (t == NB_E - 1) off_e[N_EDGES] = se;
    if (t == NB_N - 1) off_n[N_NODES] = sn;
}

__global__ void scan_k3(const int* __restrict__ counts_e,
                        const int* __restrict__ counts_n,
                        const int* __restrict__ aux,
                        int* __restrict__ off_e,
                        int* __restrict__ off_n) {
    __shared__ int sdata[256];
    int t = threadIdx.x;
    bool is_edge = blockIdx.x < NB_E;
    const int* in = is_edge ? counts_e : counts_n;
    int n = is_edge ? N_EDGES : N_NODES;
    int blk = is_edge ? blockIdx.x : (blockIdx.x - NB_E);
    int* out = is_edge ? off_e : off_n;
    int auxv = aux[blockIdx.x];
    int base = blk * 2048 + t * 8;
    int vals[8];
    int s = 0;
#pragma unroll
    for (int j = 0; j < 8; j++) {
        int idx = base + j;
        vals[j] = (idx < n) ? in[idx] : 0;
        s += vals[j];
    }
    sdata[t] = s;
    __syncthreads();
    for (int off = 1; off < 256; off <<= 1) {
        int add = (t >= off) ? sdata[t - off] : 0;
        __syncthreads();
        sdata[t] += add;
        __syncthreads();
    }
    int prefix = auxv + sdata[t] - s;
#pragma unroll
    for (int j = 0; j < 8; j++) {
        int idx = base + j;
        if (idx < n) out[idx] = prefix;
        prefix += vals[j];
    }
}

__global__ void fill_csr(const int* __restrict__ node_idx,
                         const int* __restrict__ edge_idx,
                         const int* __restrict__ off_e,
                         const int* __restrict__ off_n,
                         int* __restrict__ cur_e,
                         int* __restrict__ cur_n,
                         int* __restrict__ csr_e_nodes,
                         int* __restrict__ csr_n_edges) {
    int i = blockIdx.x * blockDim.x + threadIdx.x;
    if (i < N_INC) {
        int e = edge_idx[i];
        int n = node_idx[i];
        int pe = off_e[e] + atomicAdd(&cur_e[e], 1);
        csr_e_nodes[pe] = n;
        int pn = off_n[n] + atomicAdd(&cur_n[n], 1);
        csr_n_edges[pn] = e;
    }
}

// ---------------- GEMM (bf16 MFMA): Y = X @ W ----------------

// prep: Wt[j][k] = bf16(W[k][j]) — 128x128 bf16, 32 KB, L1/L2-resident
__global__ void wt_prep(const float* __restrict__ W, __bf16* __restrict__ Wt) {
    int i = blockIdx.x * blockDim.x + threadIdx.x; // 16384
    int k = i >> 7, j = i & 127;
    Wt[j * 128 + k] = (__bf16)W[i];
}

// Each wave: 16 rows x 128 cols. Block 256 = 4 waves = 64 rows. No LDS.
// A-frag: A[m = lane&15][k = (lane>>4)*8 + j]  (from global X, fp32->bf16)
// B-frag: B[k = (lane>>4)*8 + j][n = lane&15]  = Wt[col][k], 16B contiguous
// C/D   : col = lane&15, row = (lane>>4)*4 + reg
__global__ __launch_bounds__(256) void gemm_mfma(const float* __restrict__ X,
                                                 const __bf16* __restrict__ Wt,
                                                 float* __restrict__ Y,
                                                 int nrows) {
    int t = threadIdx.x;
    int wave = t >> 6;
    int lane = t & 63;
    int quad = lane >> 4;
    int lr = lane & 15;
    int m0 = blockIdx.x * 64 + wave * 16;
    int row = m0 + lr;
    bool rowok = row < nrows;

    f32x4 acc[8];
#pragma unroll
    for (int c = 0; c < 8; c++) acc[c] = (f32x4){0.f, 0.f, 0.f, 0.f};

    const float* xrow = X + (size_t)(rowok ? row : 0) * D + quad * 8;

#pragma unroll
    for (int kk = 0; kk < 4; kk++) {
        float4 x0, x1;
        if (rowok) {
            x0 = *(const float4*)(xrow + kk * 32);
            x1 = *(const float4*)(xrow + kk * 32 + 4);
        } else {
            x0 = make_float4(0.f, 0.f, 0.f, 0.f);
            x1 = x0;
        }
        bf16x8 a;
        a[0] = (__bf16)x0.x; a[1] = (__bf16)x0.y; a[2] = (__bf16)x0.z; a[3] = (__bf16)x0.w;
        a[4] = (__bf16)x1.x; a[5] = (__bf16)x1.y; a[6] = (__bf16)x1.z; a[7] = (__bf16)x1.w;
#pragma unroll
        for (int c = 0; c < 8; c++) {
            bf16x8 b = *(const bf16x8*)(Wt + (c * 16 + lr) * 128 + kk * 32 + quad * 8);
            acc[c] = __builtin_amdgcn_mfma_f32_16x16x32_bf16(a, b, acc[c], 0, 0, 0);
        }
    }

#pragma unroll
    for (int r = 0; r < 4; r++) {
        int row_out = m0 + quad * 4 + r;
        if (row_out < nrows) {
#pragma unroll
            for (int c = 0; c < 8; c++)
                Y[(size_t)row_out * D + c * 16 + lr] = acc[c][r];
        }
    }
}

// ---------------- Gather phases (float4, 32 lanes per segment) ----------------

__global__ __launch_bounds__(128) void edge_gather(const float* __restrict__ XW,
                                                   const int* __restrict__ off_e,
                                                   const int* __restrict__ csr_e_nodes,
                                                   float* __restrict__ ef) {
    int e = blockIdx.x * 4 + (threadIdx.x >> 5);
    int lane = threadIdx.x & 31;
    int s = off_e[e], tend = off_e[e + 1];
    float4 a0 = make_float4(0.f, 0.f, 0.f, 0.f), a1 = a0, a2 = a0, a3 = a0;
    int j = s;
    for (; j + 4 <= tend; j += 4) {
        int n0 = csr_e_nodes[j];
        int n1 = csr_e_nodes[j + 1];
        int n2 = csr_e_nodes[j + 2];
        int n3 = csr_e_nodes[j + 3];
        float4 v0 = ((const float4*)XW)[n0 * 32 + lane];
        float4 v1 = ((const float4*)XW)[n1 * 32 + lane];
        float4 v2 = ((const float4*)XW)[n2 * 32 + lane];
        float4 v3 = ((const float4*)XW)[n3 * 32 + lane];
        a0.x += v0.x; a0.y += v0.y; a0.z += v0.z; a0.w += v0.w;
        a1.x += v1.x; a1.y += v1.y; a1.z += v1.z; a1.w += v1.w;
        a2.x += v2.x; a2.y += v2.y; a2.z += v2.z; a2.w += v2.w;
        a3.x += v3.x; a3.y += v3.y; a3.z += v3.z; a3.w += v3.w;
    }
    for (; j < tend; j++) {
        float4 v = ((const float4*)XW)[csr_e_nodes[j] * 32 + lane];
        a0.x += v.x; a0.y += v.y; a0.z += v.z; a0.w += v.w;
    }
    int cnt = tend - s;
    float binv = (cnt > 0) ? 1.0f / (float)cnt : 0.0f;
    float4 r;
    r.x = (a0.x + a1.x + a2.x + a3.x) * binv;
    r.y = (a0.y + a1.y + a2.y + a3.y) * binv;
    r.z = (a0.z + a1.z + a2.z + a3.z) * binv;
    r.w = (a0.w + a1.w + a2.w + a3.w) * binv;
    ((float4*)ef)[e * 32 + lane] = r;
}

__global__ __launch_bounds__(128) void node_gather(const float* __restrict__ ef,
                                                   const int* __restrict__ off_n,
                                                   const int* __restrict__ csr_n_edges,
                                                   const float* __restrict__ bias,
                                                   float* __restrict__ out,
                                                   int relu) {
    int n = blockIdx.x * 4 + (threadIdx.x >> 5);
    int lane = threadIdx.x & 31;
    int s = off_n[n], tend = off_n[n + 1];
    float4 a0 = make_float4(0.f, 0.f, 0.f, 0.f), a1 = a0, a2 = a0, a3 = a0;
    int j = s;
    for (; j + 4 <= tend; j += 4) {
        int e0 = csr_n_edges[j];
        int e1 = csr_n_edges[j + 1];
        int e2 = csr_n_edges[j + 2];
        int e3 = csr_n_edges[j + 3];
        float4 v0 = ((const float4*)ef)[e0 * 32 + lane];
        float4 v1 = ((const float4*)ef)[e1 * 32 + lane];
        float4 v2 = ((const float4*)ef)[e2 * 32 + lane];
        float4 v3 = ((const float4*)ef)[e3 * 32 + lane];
        a0.x += v0.x; a0.y += v0.y; a0.z += v0.z; a0.w += v0.w;
        a1.x += v1.x; a1.y += v1.y; a1.z += v1.z; a1.w += v1.w;
        a2.x += v2.x; a2.y += v2.y; a2.z += v2.z; a2.w += v2.w;
        a3.x += v3.x; a3.y += v3.y; a3.z += v3.z; a3.w += v3.w;
    }
    for (; j < tend; j++) {
        float4 v = ((const float4*)ef)[csr_n_edges[j] * 32 + lane];
        a0.x += v.x; a0.y += v.y; a0.z += v.z; a0.w += v.w;
    }
    int cnt = tend - s;
    float dinv = (cnt > 0) ? 1.0f / (float)cnt : 0.0f;
    float4 b = ((const float4*)bias)[lane];
    float4 r;
    r.x = (a0.x + a1.x + a2.x + a3.x) * dinv + b.x;
    r.y = (a0.y + a1.y + a2.y + a3.y) * dinv + b.y;
    r.z = (a0.z + a1.z + a2.z + a3.z) * dinv + b.z;
    r.w = (a0.w + a1.w + a2.w + a3.w) * dinv + b.w;
    if (relu) {
        r.x = fmaxf(r.x, 0.f); r.y = fmaxf(r.y, 0.f);
        r.z = fmaxf(r.z, 0.f); r.w = fmaxf(r.w, 0.f);
    }
    ((float4*)out)[n * 32 + lane] = r;
}

// ---------------- launch ----------------

extern "C" void kernel_launch(void* const* d_in, const int* in_sizes, int n_in,
                              void* d_out, int out_size, void* d_ws, size_t ws_size,
                              hipStream_t stream) {
    const float* x        = (const float*)d_in[0];
    const int* node_idx   = (const int*)d_in[1];
    const int* edge_idx   = (const int*)d_in[2];
    const float* attr     = (const float*)d_in[3];
    const float* Wl[3]    = {(const float*)d_in[4], (const float*)d_in[6], (const float*)d_in[8]};
    const float* bl[3]    = {(const float*)d_in[5], (const float*)d_in[7], (const float*)d_in[9]};
    float* out = (float*)d_out;

    char* ws = (char*)d_ws;
    float* XW   = (float*)ws;                       // [0 .. 51,200,000)
    float* ef   = (float*)(ws + 51200000);          // [51,200,000 .. 64,000,000)
    int* counts = (int*)(ws + 64000000);            // [64,000,000 .. 65,000,000)
    int* counts_e = counts;
    int* counts_n = counts + N_EDGES;
    int* cur_e    = counts + N_EDGES + N_NODES;
    int* cur_n    = counts + 2 * N_EDGES + N_NODES;
    int* off_e  = (int*)(ws + 65000000);            // 25001 ints  -> ends 65,100,004
    int* off_n  = off_e + (N_EDGES + 1);            // 100001 ints -> ends 65,500,008
    int* aux    = off_n + (N_NODES + 1);            // 62 ints     -> ends 65,500,256
    __bf16* Wt  = (__bf16*)(ws + 65550000);         // 32,768 B    -> ends 65,582,768 (16B-aligned, in the gap before csr_e)
    int* csr_e  = (int*)(ws + 65600000);            // 600000 ints -> ends 68,000,000
    int* csr_n  = (int*)(ws + 68000000);            // 600000 ints -> ends 70,400,000

    hipMemsetAsync(counts, 0, (2 * N_EDGES + 2 * N_NODES) * sizeof(int), stream);

    count_kernel<<<(N_INC + 255) / 256, 256, 0, stream>>>(node_idx, edge_idx, counts_e, counts_n);
    scan_k1<<<NB_E + NB_N, 256, 0, stream>>>(counts_e, counts_n, aux);
    scan_k2<<<1, 64, 0, stream>>>(aux, off_e, off_n);
    scan_k3<<<NB_E + NB_N, 256, 0, stream>>>(counts_e, counts_n, aux, off_e, off_n);
    fill_csr<<<(N_INC + 255) / 256, 256, 0, stream>>>(node_idx, edge_idx, off_e, off_n,
                                                      cur_e, cur_n, csr_e, csr_n);

    const float* Xin = x;
    for (int l = 0; l < 3; l++) {
        wt_prep<<<64, 256, 0, stream>>>(Wl[l], Wt);
        gemm_mfma<<<(N_NODES + 63) / 64, 256, 0, stream>>>(Xin, Wt, XW, N_NODES);
        edge_gather<<<N_EDGES / 4, 128, 0, stream>>>(XW, off_e, csr_e, ef);
        node_gather<<<N_NODES / 4, 128, 0, stream>>>(ef, off_n, csr_n, bl[l], out, (l < 2) ? 1 : 0);
        Xin = out;
    }

    hipMemcpyAsync(out + N_NODES * D, attr, N_EDGES * 32 * sizeof(float),
                   hipMemcpyDeviceToDevice, stream);
}

// Round 5
// 424.894 us; speedup vs baseline: 2.1390x; 1.5003x over previous
//
#include <hip/hip_runtime.h>

#define N_NODES 100000
#define N_EDGES 25000
#define N_INC   600000
#define D       128
#define NB_EB   98    // edge buckets: 256 edges each (e>>8)
#define NB_NB   196   // node buckets: 512 nodes each (n>>9)
#define NCHUNK  147   // ceil(600000/4096) chunks of 4096 incidences

typedef __bf16 bf16x8 __attribute__((ext_vector_type(8)));
typedef float  f32x4  __attribute__((ext_vector_type(4)));

// ---------------- CSR build: bucket-partitioned, LDS-coalesced ----------------

__global__ __launch_bounds__(256) void bhist(const int* __restrict__ ni,
                                             const int* __restrict__ ei,
                                             int* __restrict__ bh_e,
                                             int* __restrict__ bh_n) {
    __shared__ int he[NB_EB], hn[NB_NB];
    int t = threadIdx.x;
    if (t < NB_EB) he[t] = 0;
    if (t < NB_NB) hn[t] = 0;
    __syncthreads();
    int base = blockIdx.x * 4096;
#pragma unroll
    for (int j = 0; j < 16; j++) {
        int i = base + t + j * 256;
        if (i < N_INC) {
            atomicAdd(&he[ei[i] >> 8], 1);
            atomicAdd(&hn[ni[i] >> 9], 1);
        }
    }
    __syncthreads();
    if (t < NB_EB && he[t]) atomicAdd(&bh_e[t], he[t]);
    if (t < NB_NB && hn[t]) atomicAdd(&bh_n[t], hn[t]);
}

__global__ __launch_bounds__(256) void bscan(const int* __restrict__ bh_e,
                                             const int* __restrict__ bh_n,
                                             int* __restrict__ boff_e,
                                             int* __restrict__ boff_n,
                                             int* __restrict__ bcur_e,
                                             int* __restrict__ bcur_n,
                                             int* __restrict__ off_e,
                                             int* __restrict__ off_n) {
    __shared__ int ss[256];
    int t = threadIdx.x;
    int v = (t < NB_EB) ? bh_e[t] : 0;
    ss[t] = v;
    __syncthreads();
    for (int off = 1; off < 256; off <<= 1) {
        int add = (t >= off) ? ss[t - off] : 0;
        __syncthreads();
        ss[t] += add;
        __syncthreads();
    }
    if (t < NB_EB) { boff_e[t] = ss[t] - v; bcur_e[t] = ss[t] - v; }
    if (t == NB_EB - 1) { boff_e[NB_EB] = ss[t]; off_e[N_EDGES] = ss[t]; }
    __syncthreads();
    int v2 = (t < NB_NB) ? bh_n[t] : 0;
    ss[t] = v2;
    __syncthreads();
    for (int off = 1; off < 256; off <<= 1) {
        int add = (t >= off) ? ss[t - off] : 0;
        __syncthreads();
        ss[t] += add;
        __syncthreads();
    }
    if (t < NB_NB) { boff_n[t] = ss[t] - v2; bcur_n[t] = ss[t] - v2; }
    if (t == NB_NB - 1) { boff_n[NB_NB] = ss[t]; off_n[N_NODES] = ss[t]; }
}

__global__ __launch_bounds__(256) void part_a(const int* __restrict__ ni,
                                              const int* __restrict__ ei,
                                              int* __restrict__ bcur_e,
                                              int* __restrict__ bcur_n,
                                              int2* __restrict__ pairs_e,
                                              int2* __restrict__ pairs_n) {
    __shared__ int he[NB_EB], hn[NB_NB], be[NB_EB], bn[NB_NB];
    int t = threadIdx.x;
    if (t < NB_EB) he[t] = 0;
    if (t < NB_NB) hn[t] = 0;
    __syncthreads();
    int base = blockIdx.x * 4096;
    int se[16], sn[16];
#pragma unroll
    for (int j = 0; j < 16; j++) {
        int i = base + t + j * 256;
        if (i < N_INC) {
            se[j] = ei[i]; sn[j] = ni[i];
            atomicAdd(&he[se[j] >> 8], 1);
            atomicAdd(&hn[sn[j] >> 9], 1);
        } else { se[j] = -1; sn[j] = -1; }
    }
    __syncthreads();
    if (t < NB_EB) be[t] = atomicAdd(&bcur_e[t], he[t]);
    if (t < NB_NB) bn[t] = atomicAdd(&bcur_n[t], hn[t]);
    __syncthreads();
    if (t < NB_EB) he[t] = 0;
    if (t < NB_NB) hn[t] = 0;
    __syncthreads();
#pragma unroll
    for (int j = 0; j < 16; j++) {
        if (se[j] >= 0) {
            int b = se[j] >> 8;
            int p = be[b] + atomicAdd(&he[b], 1);
            pairs_e[p] = make_int2(sn[j], se[j]);     // (node, edge)
            int b2 = sn[j] >> 9;
            int p2 = bn[b2] + atomicAdd(&hn[b2], 1);
            pairs_n[p2] = make_int2(se[j], sn[j]);    // (edge, node)
        }
    }
}

__global__ __launch_bounds__(256) void part_b_e(const int2* __restrict__ pairs_e,
                                                const int* __restrict__ boff_e,
                                                int* __restrict__ off_e,
                                                int* __restrict__ csr_e) {
    __shared__ int ss[256], cur[256];
    int b = blockIdx.x, t = threadIdx.x;
    int r0 = boff_e[b], r1 = boff_e[b + 1];
    cur[t] = 0;
    __syncthreads();
    for (int i = r0 + t; i < r1; i += 256) atomicAdd(&cur[pairs_e[i].y & 255], 1);
    __syncthreads();
    int v = cur[t];
    ss[t] = v;
    __syncthreads();
    for (int off = 1; off < 256; off <<= 1) {
        int add = (t >= off) ? ss[t - off] : 0;
        __syncthreads();
        ss[t] += add;
        __syncthreads();
    }
    int my = r0 + ss[t] - v;
    int e_id = b * 256 + t;
    if (e_id < N_EDGES) off_e[e_id] = my;
    __syncthreads();
    cur[t] = my;
    __syncthreads();
    for (int i = r0 + t; i < r1; i += 256) {
        int2 u = pairs_e[i];
        int p = atomicAdd(&cur[u.y & 255], 1);
        csr_e[p] = u.x;
    }
}

__global__ __launch_bounds__(512) void part_b_n(const int2* __restrict__ pairs_n,
                                                const int* __restrict__ boff_n,
                                                int* __restrict__ off_n,
                                                int* __restrict__ csr_n) {
    __shared__ int ss[512], cur[512];
    int b = blockIdx.x, t = threadIdx.x;
    int r0 = boff_n[b], r1 = boff_n[b + 1];
    cur[t] = 0;
    __syncthreads();
    for (int i = r0 + t; i < r1; i += 512) atomicAdd(&cur[pairs_n[i].y & 511], 1);
    __syncthreads();
    int v = cur[t];
    ss[t] = v;
    __syncthreads();
    for (int off = 1; off < 512; off <<= 1) {
        int add = (t >= off) ? ss[t - off] : 0;
        __syncthreads();
        ss[t] += add;
        __syncthreads();
    }
    int my = r0 + ss[t] - v;
    int n_id = b * 512 + t;
    if (n_id < N_NODES) off_n[n_id] = my;
    __syncthreads();
    cur[t] = my;
    __syncthreads();
    for (int i = r0 + t; i < r1; i += 512) {
        int2 u = pairs_n[i];
        int p = atomicAdd(&cur[u.y & 511], 1);
        csr_n[p] = u.x;
    }
}

// ---------------- GEMM (bf16 MFMA): Y_bf16 = X @ W ----------------

__global__ void wt_prep(const float* __restrict__ W, __bf16* __restrict__ Wt) {
    int i = blockIdx.x * blockDim.x + threadIdx.x; // 16384
    int k = i >> 7, j = i & 127;
    Wt[j * 128 + k] = (__bf16)W[i];
}

__global__ __launch_bounds__(256) void gemm_f32in(const float* __restrict__ X,
                                                  const __bf16* __restrict__ Wt,
                                                  __bf16* __restrict__ Y,
                                                  int nrows) {
    int t = threadIdx.x;
    int wave = t >> 6;
    int lane = t & 63;
    int quad = lane >> 4;
    int lr = lane & 15;
    int m0 = blockIdx.x * 64 + wave * 16;
    int row = m0 + lr;
    bool rowok = row < nrows;

    f32x4 acc[8];
#pragma unroll
    for (int c = 0; c < 8; c++) acc[c] = (f32x4){0.f, 0.f, 0.f, 0.f};

    const float* xrow = X + (size_t)(rowok ? row : 0) * D + quad * 8;

#pragma unroll
    for (int kk = 0; kk < 4; kk++) {
        float4 x0, x1;
        if (rowok) {
            x0 = *(const float4*)(xrow + kk * 32);
            x1 = *(const float4*)(xrow + kk * 32 + 4);
        } else {
            x0 = make_float4(0.f, 0.f, 0.f, 0.f);
            x1 = x0;
        }
        bf16x8 a;
        a[0] = (__bf16)x0.x; a[1] = (__bf16)x0.y; a[2] = (__bf16)x0.z; a[3] = (__bf16)x0.w;
        a[4] = (__bf16)x1.x; a[5] = (__bf16)x1.y; a[6] = (__bf16)x1.z; a[7] = (__bf16)x1.w;
#pragma unroll
        for (int c = 0; c < 8; c++) {
            bf16x8 b = *(const bf16x8*)(Wt + (c * 16 + lr) * 128 + kk * 32 + quad * 8);
            acc[c] = __builtin_amdgcn_mfma_f32_16x16x32_bf16(a, b, acc[c], 0, 0, 0);
        }
    }

#pragma unroll
    for (int r = 0; r < 4; r++) {
        int row_out = m0 + quad * 4 + r;
        if (row_out < nrows) {
#pragma unroll
            for (int c = 0; c < 8; c++)
                Y[(size_t)row_out * D + c * 16 + lr] = (__bf16)acc[c][r];
        }
    }
}

__global__ __launch_bounds__(256) void gemm_bf16in(const __bf16* __restrict__ X,
                                                   const __bf16* __restrict__ Wt,
                                                   __bf16* __restrict__ Y,
                                                   int nrows) {
    int t = threadIdx.x;
    int wave = t >> 6;
    int lane = t & 63;
    int quad = lane >> 4;
    int lr = lane & 15;
    int m0 = blockIdx.x * 64 + wave * 16;
    int row = m0 + lr;
    bool rowok = row < nrows;

    f32x4 acc[8];
#pragma unroll
    for (int c = 0; c < 8; c++) acc[c] = (f32x4){0.f, 0.f, 0.f, 0.f};

    const __bf16* xrow = X + (size_t)(rowok ? row : 0) * D + quad * 8;

#pragma unroll
    for (int kk = 0; kk < 4; kk++) {
        bf16x8 a = *(const bf16x8*)(xrow + kk * 32);
#pragma unroll
        for (int c = 0; c < 8; c++) {
            bf16x8 b = *(const bf16x8*)(Wt + (c * 16 + lr) * 128 + kk * 32 + quad * 8);
            acc[c] = __builtin_amdgcn_mfma_f32_16x16x32_bf16(a, b, acc[c], 0, 0, 0);
        }
    }

#pragma unroll
    for (int r = 0; r < 4; r++) {
        int row_out = m0 + quad * 4 + r;
        if (row_out < nrows) {
#pragma unroll
            for (int c = 0; c < 8; c++)
                Y[(size_t)row_out * D + c * 16 + lr] = (__bf16)acc[c][r];
        }
    }
}

// ---------------- Gather phases (bf16 rows, fp32 accumulate) ----------------
// 16 lanes per segment x bf16x8 = 128 elements; 8 segments per 128-thread block.

__global__ __launch_bounds__(128) void edge_gather(const __bf16* __restrict__ XW,
                                                   const int* __restrict__ off_e,
                                                   const int* __restrict__ csr_e,
                                                   __bf16* __restrict__ ef) {
    int e = blockIdx.x * 8 + (threadIdx.x >> 4);
    int lane = threadIdx.x & 15;
    int s = off_e[e], tend = off_e[e + 1];
    float acc[8] = {0.f, 0.f, 0.f, 0.f, 0.f, 0.f, 0.f, 0.f};
    int j = s;
    for (; j + 4 <= tend; j += 4) {
        int n0 = csr_e[j], n1 = csr_e[j + 1], n2 = csr_e[j + 2], n3 = csr_e[j + 3];
        bf16x8 v0 = *(const bf16x8*)(XW + n0 * 128 + lane * 8);
        bf16x8 v1 = *(const bf16x8*)(XW + n1 * 128 + lane * 8);
        bf16x8 v2 = *(const bf16x8*)(XW + n2 * 128 + lane * 8);
        bf16x8 v3 = *(const bf16x8*)(XW + n3 * 128 + lane * 8);
#pragma unroll
        for (int k = 0; k < 8; k++)
            acc[k] += ((float)v0[k] + (float)v1[k]) + ((float)v2[k] + (float)v3[k]);
    }
    for (; j < tend; j++) {
        bf16x8 v = *(const bf16x8*)(XW + csr_e[j] * 128 + lane * 8);
#pragma unroll
        for (int k = 0; k < 8; k++) acc[k] += (float)v[k];
    }
    int cnt = tend - s;
    float binv = (cnt > 0) ? 1.0f / (float)cnt : 0.0f;
    bf16x8 r;
#pragma unroll
    for (int k = 0; k < 8; k++) r[k] = (__bf16)(acc[k] * binv);
    *(bf16x8*)(ef + e * 128 + lane * 8) = r;
}

// mode 0: relu, bf16 out to hb; mode 1: no relu, fp32 out to of
__global__ __launch_bounds__(128) void node_gather(const __bf16* __restrict__ ef,
                                                   const int* __restrict__ off_n,
                                                   const int* __restrict__ csr_n,
                                                   const float* __restrict__ bias,
                                                   __bf16* __restrict__ hb,
                                                   float* __restrict__ of,
                                                   int mode) {
    int n = blockIdx.x * 8 + (threadIdx.x >> 4);
    int lane = threadIdx.x & 15;
    int s = off_n[n], tend = off_n[n + 1];
    float acc[8] = {0.f, 0.f, 0.f, 0.f, 0.f, 0.f, 0.f, 0.f};
    int j = s;
    for (; j + 4 <= tend; j += 4) {
        int e0 = csr_n[j], e1 = csr_n[j + 1], e2 = csr_n[j + 2], e3 = csr_n[j + 3];
        bf16x8 v0 = *(const bf16x8*)(ef + e0 * 128 + lane * 8);
        bf16x8 v1 = *(const bf16x8*)(ef + e1 * 128 + lane * 8);
        bf16x8 v2 = *(const bf16x8*)(ef + e2 * 128 + lane * 8);
        bf16x8 v3 = *(const bf16x8*)(ef + e3 * 128 + lane * 8);
#pragma unroll
        for (int k = 0; k < 8; k++)
            acc[k] += ((float)v0[k] + (float)v1[k]) + ((float)v2[k] + (float)v3[k]);
    }
    for (; j < tend; j++) {
        bf16x8 v = *(const bf16x8*)(ef + csr_n[j] * 128 + lane * 8);
#pragma unroll
        for (int k = 0; k < 8; k++) acc[k] += (float)v[k];
    }
    int cnt = tend - s;
    float dinv = (cnt > 0) ? 1.0f / (float)cnt : 0.0f;
    float4 b0 = ((const float4*)bias)[lane * 2];
    float4 b1 = ((const float4*)bias)[lane * 2 + 1];
    float vals[8];
    vals[0] = acc[0] * dinv + b0.x; vals[1] = acc[1] * dinv + b0.y;
    vals[2] = acc[2] * dinv + b0.z; vals[3] = acc[3] * dinv + b0.w;
    vals[4] = acc[4] * dinv + b1.x; vals[5] = acc[5] * dinv + b1.y;
    vals[6] = acc[6] * dinv + b1.z; vals[7] = acc[7] * dinv + b1.w;
    if (mode == 0) {
        bf16x8 r;
#pragma unroll
        for (int k = 0; k < 8; k++) r[k] = (__bf16)fmaxf(vals[k], 0.f);
        *(bf16x8*)(hb + n * 128 + lane * 8) = r;
    } else {
        float4 o0 = make_float4(vals[0], vals[1], vals[2], vals[3]);
        float4 o1 = make_float4(vals[4], vals[5], vals[6], vals[7]);
        ((float4*)of)[n * 32 + lane * 2] = o0;
        ((float4*)of)[n * 32 + lane * 2 + 1] = o1;
    }
}

// ---------------- launch ----------------

extern "C" void kernel_launch(void* const* d_in, const int* in_sizes, int n_in,
                              void* d_out, int out_size, void* d_ws, size_t ws_size,
                              hipStream_t stream) {
    const float* x        = (const float*)d_in[0];
    const int* node_idx   = (const int*)d_in[1];
    const int* edge_idx   = (const int*)d_in[2];
    const float* attr     = (const float*)d_in[3];
    const float* Wl[3]    = {(const float*)d_in[4], (const float*)d_in[6], (const float*)d_in[8]};
    const float* bl[3]    = {(const float*)d_in[5], (const float*)d_in[7], (const float*)d_in[9]};
    float* out = (float*)d_out;

    char* ws = (char*)d_ws;
    __bf16* XW = (__bf16*)ws;                   // [0 .. 25,600,000)
    __bf16* Hb = (__bf16*)(ws + 25600000);      // [25,600,000 .. 51,200,000)
    __bf16* EF = (__bf16*)(ws + 51200000);      // [51,200,000 .. 57,600,000)
    int* csr_e = (int*)(ws + 57600000);         // 2,400,000 B
    int* csr_n = (int*)(ws + 60000000);         // 2,400,000 B
    int* off_e = (int*)(ws + 62400000);         // 100,004 B
    int* off_n = (int*)(ws + 62500008);         // 400,004 B
    int* ib    = (int*)(ws + 62900016);         // small int arrays, 884 ints
    int* bh_e   = ib;            // 98
    int* bh_n   = ib + 98;       // 196
    int* boff_e = ib + 294;      // 99
    int* boff_n = ib + 393;      // 197
    int* bcur_e = ib + 590;      // 98
    int* bcur_n = ib + 688;      // 196
    __bf16* Wt = (__bf16*)(ws + 62910000);      // 32,768 B -> ends 62,942,768
    // pairs arrays live in XW/Hb region during CSR build (dead before first gemm writes XW)
    int2* pairs_e = (int2*)ws;                  // [0 .. 4,800,000)
    int2* pairs_n = (int2*)(ws + 4800000);      // [4,800,000 .. 9,600,000)

    hipMemsetAsync(bh_e, 0, 294 * sizeof(int), stream);

    bhist<<<NCHUNK, 256, 0, stream>>>(node_idx, edge_idx, bh_e, bh_n);
    bscan<<<1, 256, 0, stream>>>(bh_e, bh_n, boff_e, boff_n, bcur_e, bcur_n, off_e, off_n);
    part_a<<<NCHUNK, 256, 0, stream>>>(node_idx, edge_idx, bcur_e, bcur_n, pairs_e, pairs_n);
    part_b_e<<<NB_EB, 256, 0, stream>>>(pairs_e, boff_e, off_e, csr_e);
    part_b_n<<<NB_NB, 512, 0, stream>>>(pairs_n, boff_n, off_n, csr_n);

    for (int l = 0; l < 3; l++) {
        wt_prep<<<64, 256, 0, stream>>>(Wl[l], Wt);
        if (l == 0)
            gemm_f32in<<<(N_NODES + 63) / 64, 256, 0, stream>>>(x, Wt, XW, N_NODES);
        else
            gemm_bf16in<<<(N_NODES + 63) / 64, 256, 0, stream>>>(Hb, Wt, XW, N_NODES);
        edge_gather<<<N_EDGES / 8, 128, 0, stream>>>(XW, off_e, csr_e, EF);
        node_gather<<<N_NODES / 8, 128, 0, stream>>>(EF, off_n, csr_n, bl[l],
                                                     Hb, out, (l < 2) ? 0 : 1);
    }

    hipMemcpyAsync(out + N_NODES * D, attr, N_EDGES * 32 * sizeof(float),
                   hipMemcpyDeviceToDevice, stream);
}

// Round 6
// 360.400 us; speedup vs baseline: 2.5218x; 1.1790x over previous
//
#include <hip/hip_runtime.h>

#define N_NODES 100000
#define N_EDGES 25000
#define N_INC   600000
#define D       128
#define NB_EB   98    // edge buckets: 256 edges each (e>>8)
#define NB_NB   196   // node buckets: 512 nodes each (n>>9)
#define NCHUNK  147   // ceil(600000/4096) chunks of 4096 incidences
#define WTS     136   // LDS stride for Wt: 128+8 -> conflict-free b128 reads, 16B-aligned rows

typedef __bf16 bf16x8 __attribute__((ext_vector_type(8)));
typedef float  f32x4  __attribute__((ext_vector_type(4)));

// ---------------- CSR build: bucket-partitioned, LDS-coalesced ----------------

__global__ __launch_bounds__(256) void bhist(const int* __restrict__ ni,
                                             const int* __restrict__ ei,
                                             int* __restrict__ bh_e,
                                             int* __restrict__ bh_n) {
    __shared__ int he[NB_EB], hn[NB_NB];
    int t = threadIdx.x;
    if (t < NB_EB) he[t] = 0;
    if (t < NB_NB) hn[t] = 0;
    __syncthreads();
    int base = blockIdx.x * 4096;
#pragma unroll
    for (int j = 0; j < 16; j++) {
        int i = base + t + j * 256;
        if (i < N_INC) {
            atomicAdd(&he[ei[i] >> 8], 1);
            atomicAdd(&hn[ni[i] >> 9], 1);
        }
    }
    __syncthreads();
    if (t < NB_EB && he[t]) atomicAdd(&bh_e[t], he[t]);
    if (t < NB_NB && hn[t]) atomicAdd(&bh_n[t], hn[t]);
}

__global__ __launch_bounds__(256) void bscan(const int* __restrict__ bh_e,
                                             const int* __restrict__ bh_n,
                                             int* __restrict__ boff_e,
                                             int* __restrict__ boff_n,
                                             int* __restrict__ bcur_e,
                                             int* __restrict__ bcur_n,
                                             int* __restrict__ off_e,
                                             int* __restrict__ off_n) {
    __shared__ int ss[256];
    int t = threadIdx.x;
    int v = (t < NB_EB) ? bh_e[t] : 0;
    ss[t] = v;
    __syncthreads();
    for (int off = 1; off < 256; off <<= 1) {
        int add = (t >= off) ? ss[t - off] : 0;
        __syncthreads();
        ss[t] += add;
        __syncthreads();
    }
    if (t < NB_EB) { boff_e[t] = ss[t] - v; bcur_e[t] = ss[t] - v; }
    if (t == NB_EB - 1) { boff_e[NB_EB] = ss[t]; off_e[N_EDGES] = ss[t]; }
    __syncthreads();
    int v2 = (t < NB_NB) ? bh_n[t] : 0;
    ss[t] = v2;
    __syncthreads();
    for (int off = 1; off < 256; off <<= 1) {
        int add = (t >= off) ? ss[t - off] : 0;
        __syncthreads();
        ss[t] += add;
        __syncthreads();
    }
    if (t < NB_NB) { boff_n[t] = ss[t] - v2; bcur_n[t] = ss[t] - v2; }
    if (t == NB_NB - 1) { boff_n[NB_NB] = ss[t]; off_n[N_NODES] = ss[t]; }
}

__global__ __launch_bounds__(256) void part_a(const int* __restrict__ ni,
                                              const int* __restrict__ ei,
                                              int* __restrict__ bcur_e,
                                              int* __restrict__ bcur_n,
                                              int2* __restrict__ pairs_e,
                                              int2* __restrict__ pairs_n) {
    __shared__ int he[NB_EB], hn[NB_NB], be[NB_EB], bn[NB_NB];
    int t = threadIdx.x;
    if (t < NB_EB) he[t] = 0;
    if (t < NB_NB) hn[t] = 0;
    __syncthreads();
    int base = blockIdx.x * 4096;
    int se[16], sn[16];
#pragma unroll
    for (int j = 0; j < 16; j++) {
        int i = base + t + j * 256;
        if (i < N_INC) {
            se[j] = ei[i]; sn[j] = ni[i];
            atomicAdd(&he[se[j] >> 8], 1);
            atomicAdd(&hn[sn[j] >> 9], 1);
        } else { se[j] = -1; sn[j] = -1; }
    }
    __syncthreads();
    if (t < NB_EB) be[t] = atomicAdd(&bcur_e[t], he[t]);
    if (t < NB_NB) bn[t] = atomicAdd(&bcur_n[t], hn[t]);
    __syncthreads();
    if (t < NB_EB) he[t] = 0;
    if (t < NB_NB) hn[t] = 0;
    __syncthreads();
#pragma unroll
    for (int j = 0; j < 16; j++) {
        if (se[j] >= 0) {
            int b = se[j] >> 8;
            int p = be[b] + atomicAdd(&he[b], 1);
            pairs_e[p] = make_int2(sn[j], se[j]);     // (node, edge)
            int b2 = sn[j] >> 9;
            int p2 = bn[b2] + atomicAdd(&hn[b2], 1);
            pairs_n[p2] = make_int2(se[j], sn[j]);    // (edge, node)
        }
    }
}

__global__ __launch_bounds__(256) void part_b_e(const int2* __restrict__ pairs_e,
                                                const int* __restrict__ boff_e,
                                                int* __restrict__ off_e,
                                                int* __restrict__ csr_e) {
    __shared__ int ss[256], cur[256];
    int b = blockIdx.x, t = threadIdx.x;
    int r0 = boff_e[b], r1 = boff_e[b + 1];
    cur[t] = 0;
    __syncthreads();
    for (int i = r0 + t; i < r1; i += 256) atomicAdd(&cur[pairs_e[i].y & 255], 1);
    __syncthreads();
    int v = cur[t];
    ss[t] = v;
    __syncthreads();
    for (int off = 1; off < 256; off <<= 1) {
        int add = (t >= off) ? ss[t - off] : 0;
        __syncthreads();
        ss[t] += add;
        __syncthreads();
    }
    int my = r0 + ss[t] - v;
    int e_id = b * 256 + t;
    if (e_id < N_EDGES) off_e[e_id] = my;
    __syncthreads();
    cur[t] = my;
    __syncthreads();
    for (int i = r0 + t; i < r1; i += 256) {
        int2 u = pairs_e[i];
        int p = atomicAdd(&cur[u.y & 255], 1);
        csr_e[p] = u.x;
    }
}

__global__ __launch_bounds__(512) void part_b_n(const int2* __restrict__ pairs_n,
                                                const int* __restrict__ boff_n,
                                                int* __restrict__ off_n,
                                                int* __restrict__ csr_n) {
    __shared__ int ss[512], cur[512];
    int b = blockIdx.x, t = threadIdx.x;
    int r0 = boff_n[b], r1 = boff_n[b + 1];
    cur[t] = 0;
    __syncthreads();
    for (int i = r0 + t; i < r1; i += 512) atomicAdd(&cur[pairs_n[i].y & 511], 1);
    __syncthreads();
    int v = cur[t];
    ss[t] = v;
    __syncthreads();
    for (int off = 1; off < 512; off <<= 1) {
        int add = (t >= off) ? ss[t - off] : 0;
        __syncthreads();
        ss[t] += add;
        __syncthreads();
    }
    int my = r0 + ss[t] - v;
    int n_id = b * 512 + t;
    if (n_id < N_NODES) off_n[n_id] = my;
    __syncthreads();
    cur[t] = my;
    __syncthreads();
    for (int i = r0 + t; i < r1; i += 512) {
        int2 u = pairs_n[i];
        int p = atomicAdd(&cur[u.y & 511], 1);
        csr_n[p] = u.x;
    }
}

// ---------------- GEMM v2 (bf16 MFMA, Wt in LDS): Y_bf16 = X @ W ----------------

__global__ void wt_prep(const float* __restrict__ W, __bf16* __restrict__ Wt) {
    int i = blockIdx.x * blockDim.x + threadIdx.x; // 16384
    int k = i >> 7, j = i & 127;
    Wt[j * 128 + k] = (__bf16)W[i];
}

// Block 256 = 4 waves; block tile = 128 rows. Wave tile = 32 rows (two 16-row
// m-tiles sharing each B ds_read). B: WtS[col*WTS + k], stride 136 -> bank
// group = 4*((lr+quad)%8): conflict-free ds_read_b128.
__global__ __launch_bounds__(256) void gemm2_bf16(const __bf16* __restrict__ X,
                                                  const __bf16* __restrict__ Wt,
                                                  __bf16* __restrict__ Y,
                                                  int nrows) {
    __shared__ __bf16 WtS[128 * WTS];
    int t = threadIdx.x;
    for (int i = t; i < 2048; i += 256) {          // 2048 16B-chunks = 32 KB
        int col = i >> 4, ch = i & 15;
        *(float4*)(WtS + col * WTS + ch * 8) = ((const float4*)Wt)[i];
    }
    __syncthreads();

    int wave = t >> 6;
    int lane = t & 63;
    int quad = lane >> 4;
    int lr = lane & 15;
    int m0 = blockIdx.x * 128 + wave * 32;         // two m-tiles: m0, m0+16

    f32x4 acc[2][8];
#pragma unroll
    for (int mt = 0; mt < 2; mt++)
#pragma unroll
        for (int c = 0; c < 8; c++) acc[mt][c] = (f32x4){0.f, 0.f, 0.f, 0.f};

    int r0 = m0 + lr;       if (r0 >= nrows) r0 = 0;
    int r1 = m0 + 16 + lr;  if (r1 >= nrows) r1 = 0;
    const __bf16* x0p = X + (size_t)r0 * D + quad * 8;
    const __bf16* x1p = X + (size_t)r1 * D + quad * 8;

#pragma unroll
    for (int kk = 0; kk < 4; kk++) {
        bf16x8 a0 = *(const bf16x8*)(x0p + kk * 32);
        bf16x8 a1 = *(const bf16x8*)(x1p + kk * 32);
#pragma unroll
        for (int c = 0; c < 8; c++) {
            bf16x8 b = *(const bf16x8*)(WtS + (c * 16 + lr) * WTS + kk * 32 + quad * 8);
            acc[0][c] = __builtin_amdgcn_mfma_f32_16x16x32_bf16(a0, b, acc[0][c], 0, 0, 0);
            acc[1][c] = __builtin_amdgcn_mfma_f32_16x16x32_bf16(a1, b, acc[1][c], 0, 0, 0);
        }
    }

#pragma unroll
    for (int mt = 0; mt < 2; mt++)
#pragma unroll
        for (int r = 0; r < 4; r++) {
            int row_out = m0 + mt * 16 + quad * 4 + r;
            if (row_out < nrows) {
#pragma unroll
                for (int c = 0; c < 8; c++)
                    Y[(size_t)row_out * D + c * 16 + lr] = (__bf16)acc[mt][c][r];
            }
        }
}

__global__ __launch_bounds__(256) void gemm2_f32(const float* __restrict__ X,
                                                 const __bf16* __restrict__ Wt,
                                                 __bf16* __restrict__ Y,
                                                 int nrows) {
    __shared__ __bf16 WtS[128 * WTS];
    int t = threadIdx.x;
    for (int i = t; i < 2048; i += 256) {
        int col = i >> 4, ch = i & 15;
        *(float4*)(WtS + col * WTS + ch * 8) = ((const float4*)Wt)[i];
    }
    __syncthreads();

    int wave = t >> 6;
    int lane = t & 63;
    int quad = lane >> 4;
    int lr = lane & 15;
    int m0 = blockIdx.x * 128 + wave * 32;

    f32x4 acc[2][8];
#pragma unroll
    for (int mt = 0; mt < 2; mt++)
#pragma unroll
        for (int c = 0; c < 8; c++) acc[mt][c] = (f32x4){0.f, 0.f, 0.f, 0.f};

    int r0 = m0 + lr;       if (r0 >= nrows) r0 = 0;
    int r1 = m0 + 16 + lr;  if (r1 >= nrows) r1 = 0;
    const float* x0p = X + (size_t)r0 * D + quad * 8;
    const float* x1p = X + (size_t)r1 * D + quad * 8;

#pragma unroll
    for (int kk = 0; kk < 4; kk++) {
        float4 u0 = *(const float4*)(x0p + kk * 32);
        float4 u1 = *(const float4*)(x0p + kk * 32 + 4);
        float4 v0 = *(const float4*)(x1p + kk * 32);
        float4 v1 = *(const float4*)(x1p + kk * 32 + 4);
        bf16x8 a0, a1;
        a0[0] = (__bf16)u0.x; a0[1] = (__bf16)u0.y; a0[2] = (__bf16)u0.z; a0[3] = (__bf16)u0.w;
        a0[4] = (__bf16)u1.x; a0[5] = (__bf16)u1.y; a0[6] = (__bf16)u1.z; a0[7] = (__bf16)u1.w;
        a1[0] = (__bf16)v0.x; a1[1] = (__bf16)v0.y; a1[2] = (__bf16)v0.z; a1[3] = (__bf16)v0.w;
        a1[4] = (__bf16)v1.x; a1[5] = (__bf16)v1.y; a1[6] = (__bf16)v1.z; a1[7] = (__bf16)v1.w;
#pragma unroll
        for (int c = 0; c < 8; c++) {
            bf16x8 b = *(const bf16x8*)(WtS + (c * 16 + lr) * WTS + kk * 32 + quad * 8);
            acc[0][c] = __builtin_amdgcn_mfma_f32_16x16x32_bf16(a0, b, acc[0][c], 0, 0, 0);
            acc[1][c] = __builtin_amdgcn_mfma_f32_16x16x32_bf16(a1, b, acc[1][c], 0, 0, 0);
        }
    }

#pragma unroll
    for (int mt = 0; mt < 2; mt++)
#pragma unroll
        for (int r = 0; r < 4; r++) {
            int row_out = m0 + mt * 16 + quad * 4 + r;
            if (row_out < nrows) {
#pragma unroll
                for (int c = 0; c < 8; c++)
                    Y[(size_t)row_out * D + c * 16 + lr] = (__bf16)acc[mt][c][r];
            }
        }
}

// ---------------- Gather phases (bf16 rows, fp32 accumulate) ----------------
// 16 lanes per segment x bf16x8 = 128 elements; 8 segments per 128-thread block.

__global__ __launch_bounds__(128) void edge_gather(const __bf16* __restrict__ XW,
                                                   const int* __restrict__ off_e,
                                                   const int* __restrict__ csr_e,
                                                   __bf16* __restrict__ ef) {
    int e = blockIdx.x * 8 + (threadIdx.x >> 4);
    int lane = threadIdx.x & 15;
    int s = off_e[e], tend = off_e[e + 1];
    float acc[8] = {0.f, 0.f, 0.f, 0.f, 0.f, 0.f, 0.f, 0.f};
    int j = s;
    for (; j + 4 <= tend; j += 4) {
        int n0 = csr_e[j], n1 = csr_e[j + 1], n2 = csr_e[j + 2], n3 = csr_e[j + 3];
        bf16x8 v0 = *(const bf16x8*)(XW + n0 * 128 + lane * 8);
        bf16x8 v1 = *(const bf16x8*)(XW + n1 * 128 + lane * 8);
        bf16x8 v2 = *(const bf16x8*)(XW + n2 * 128 + lane * 8);
        bf16x8 v3 = *(const bf16x8*)(XW + n3 * 128 + lane * 8);
#pragma unroll
        for (int k = 0; k < 8; k++)
            acc[k] += ((float)v0[k] + (float)v1[k]) + ((float)v2[k] + (float)v3[k]);
    }
    for (; j < tend; j++) {
        bf16x8 v = *(const bf16x8*)(XW + csr_e[j] * 128 + lane * 8);
#pragma unroll
        for (int k = 0; k < 8; k++) acc[k] += (float)v[k];
    }
    int cnt = tend - s;
    float binv = (cnt > 0) ? 1.0f / (float)cnt : 0.0f;
    bf16x8 r;
#pragma unroll
    for (int k = 0; k < 8; k++) r[k] = (__bf16)(acc[k] * binv);
    *(bf16x8*)(ef + e * 128 + lane * 8) = r;
}

// mode 0: relu, bf16 out to hb; mode 1: no relu, fp32 out to of
__global__ __launch_bounds__(128) void node_gather(const __bf16* __restrict__ ef,
                                                   const int* __restrict__ off_n,
                                                   const int* __restrict__ csr_n,
                                                   const float* __restrict__ bias,
                                                   __bf16* __restrict__ hb,
                                                   float* __restrict__ of,
                                                   int mode) {
    int n = blockIdx.x * 8 + (threadIdx.x >> 4);
    int lane = threadIdx.x & 15;
    int s = off_n[n], tend = off_n[n + 1];
    float acc[8] = {0.f, 0.f, 0.f, 0.f, 0.f, 0.f, 0.f, 0.f};
    int j = s;
    for (; j + 4 <= tend; j += 4) {
        int e0 = csr_n[j], e1 = csr_n[j + 1], e2 = csr_n[j + 2], e3 = csr_n[j + 3];
        bf16x8 v0 = *(const bf16x8*)(ef + e0 * 128 + lane * 8);
        bf16x8 v1 = *(const bf16x8*)(ef + e1 * 128 + lane * 8);
        bf16x8 v2 = *(const bf16x8*)(ef + e2 * 128 + lane * 8);
        bf16x8 v3 = *(const bf16x8*)(ef + e3 * 128 + lane * 8);
#pragma unroll
        for (int k = 0; k < 8; k++)
            acc[k] += ((float)v0[k] + (float)v1[k]) + ((float)v2[k] + (float)v3[k]);
    }
    for (; j < tend; j++) {
        bf16x8 v = *(const bf16x8*)(ef + csr_n[j] * 128 + lane * 8);
#pragma unroll
        for (int k = 0; k < 8; k++) acc[k] += (float)v[k];
    }
    int cnt = tend - s;
    float dinv = (cnt > 0) ? 1.0f / (float)cnt : 0.0f;
    float4 b0 = ((const float4*)bias)[lane * 2];
    float4 b1 = ((const float4*)bias)[lane * 2 + 1];
    float vals[8];
    vals[0] = acc[0] * dinv + b0.x; vals[1] = acc[1] * dinv + b0.y;
    vals[2] = acc[2] * dinv + b0.z; vals[3] = acc[3] * dinv + b0.w;
    vals[4] = acc[4] * dinv + b1.x; vals[5] = acc[5] * dinv + b1.y;
    vals[6] = acc[6] * dinv + b1.z; vals[7] = acc[7] * dinv + b1.w;
    if (mode == 0) {
        bf16x8 r;
#pragma unroll
        for (int k = 0; k < 8; k++) r[k] = (__bf16)fmaxf(vals[k], 0.f);
        *(bf16x8*)(hb + n * 128 + lane * 8) = r;
    } else {
        float4 o0 = make_float4(vals[0], vals[1], vals[2], vals[3]);
        float4 o1 = make_float4(vals[4], vals[5], vals[6], vals[7]);
        ((float4*)of)[n * 32 + lane * 2] = o0;
        ((float4*)of)[n * 32 + lane * 2 + 1] = o1;
    }
}

// ---------------- launch ----------------

extern "C" void kernel_launch(void* const* d_in, const int* in_sizes, int n_in,
                              void* d_out, int out_size, void* d_ws, size_t ws_size,
                              hipStream_t stream) {
    const float* x        = (const float*)d_in[0];
    const int* node_idx   = (const int*)d_in[1];
    const int* edge_idx   = (const int*)d_in[2];
    const float* attr     = (const float*)d_in[3];
    const float* Wl[3]    = {(const float*)d_in[4], (const float*)d_in[6], (const float*)d_in[8]};
    const float* bl[3]    = {(const float*)d_in[5], (const float*)d_in[7], (const float*)d_in[9]};
    float* out = (float*)d_out;

    char* ws = (char*)d_ws;
    __bf16* XW = (__bf16*)ws;                   // [0 .. 25,600,000)
    __bf16* Hb = (__bf16*)(ws + 25600000);      // [25,600,000 .. 51,200,000)
    __bf16* EF = (__bf16*)(ws + 51200000);      // [51,200,000 .. 57,600,000)
    int* csr_e = (int*)(ws + 57600000);         // 2,400,000 B
    int* csr_n = (int*)(ws + 60000000);         // 2,400,000 B
    int* off_e = (int*)(ws + 62400000);         // 100,004 B
    int* off_n = (int*)(ws + 62500008);         // 400,004 B
    int* ib    = (int*)(ws + 62900016);         // small int arrays
    int* bh_e   = ib;            // 98
    int* bh_n   = ib + 98;       // 196
    int* boff_e = ib + 294;      // 99
    int* boff_n = ib + 393;      // 197
    int* bcur_e = ib + 590;      // 98
    int* bcur_n = ib + 688;      // 196
    __bf16* Wt = (__bf16*)(ws + 62910000);      // 32,768 B -> ends 62,942,768
    int2* pairs_e = (int2*)ws;                  // CSR-build phase only
    int2* pairs_n = (int2*)(ws + 4800000);

    hipMemsetAsync(bh_e, 0, 294 * sizeof(int), stream);

    bhist<<<NCHUNK, 256, 0, stream>>>(node_idx, edge_idx, bh_e, bh_n);
    bscan<<<1, 256, 0, stream>>>(bh_e, bh_n, boff_e, boff_n, bcur_e, bcur_n, off_e, off_n);
    part_a<<<NCHUNK, 256, 0, stream>>>(node_idx, edge_idx, bcur_e, bcur_n, pairs_e, pairs_n);
    part_b_e<<<NB_EB, 256, 0, stream>>>(pairs_e, boff_e, off_e, csr_e);
    part_b_n<<<NB_NB, 512, 0, stream>>>(pairs_n, boff_n, off_n, csr_n);

    for (int l = 0; l < 3; l++) {
        wt_prep<<<64, 256, 0, stream>>>(Wl[l], Wt);
        if (l == 0)
            gemm2_f32<<<(N_NODES + 127) / 128, 256, 0, stream>>>(x, Wt, XW, N_NODES);
        else
            gemm2_bf16<<<(N_NODES + 127) / 128, 256, 0, stream>>>(Hb, Wt, XW, N_NODES);
        edge_gather<<<N_EDGES / 8, 128, 0, stream>>>(XW, off_e, csr_e, EF);
        node_gather<<<N_NODES / 8, 128, 0, stream>>>(EF, off_n, csr_n, bl[l],
                                                     Hb, out, (l < 2) ? 0 : 1);
    }

    hipMemcpyAsync(out + N_NODES * D, attr, N_EDGES * 32 * sizeof(float),
                   hipMemcpyDeviceToDevice, stream);
}

// Round 7
// 351.451 us; speedup vs baseline: 2.5860x; 1.0255x over previous
//
#include <hip/hip_runtime.h>

#define N_NODES 100000
#define N_EDGES 25000
#define N_INC   600000
#define D       128
#define NB_EB   98    // edge buckets: 256 edges each (e>>8)
#define NB_NB   196   // node buckets: 512 nodes each (n>>9)
#define NCHUNK  147   // ceil(600000/4096) chunks of 4096 incidences
#define WTS     136   // LDS stride for Wt: conflict-free b128 reads, 16B-aligned rows

typedef __bf16 bf16x8 __attribute__((ext_vector_type(8)));
typedef float  f32x4  __attribute__((ext_vector_type(4)));

// ---------------- fp32 -> bf16 cast (x only, once) ----------------

__global__ __launch_bounds__(256) void to_bf16(const float* __restrict__ X,
                                               __bf16* __restrict__ Y, int n8) {
    int i = blockIdx.x * blockDim.x + threadIdx.x;
    if (i < n8) {
        float4 a = ((const float4*)X)[i * 2];
        float4 b = ((const float4*)X)[i * 2 + 1];
        bf16x8 r;
        r[0] = (__bf16)a.x; r[1] = (__bf16)a.y; r[2] = (__bf16)a.z; r[3] = (__bf16)a.w;
        r[4] = (__bf16)b.x; r[5] = (__bf16)b.y; r[6] = (__bf16)b.z; r[7] = (__bf16)b.w;
        *(bf16x8*)(Y + i * 8) = r;
    }
}

// ---------------- CSR build: bucket-partitioned, packed 32-bit pairs ----------------

__global__ __launch_bounds__(256) void bhist(const int* __restrict__ ni,
                                             const int* __restrict__ ei,
                                             int* __restrict__ bh_e,
                                             int* __restrict__ bh_n) {
    __shared__ int he[NB_EB], hn[NB_NB];
    int t = threadIdx.x;
    if (t < NB_EB) he[t] = 0;
    if (t < NB_NB) hn[t] = 0;
    __syncthreads();
    int base = blockIdx.x * 4096;
#pragma unroll
    for (int j = 0; j < 16; j++) {
        int i = base + t + j * 256;
        if (i < N_INC) {
            atomicAdd(&he[ei[i] >> 8], 1);
            atomicAdd(&hn[ni[i] >> 9], 1);
        }
    }
    __syncthreads();
    if (t < NB_EB && he[t]) atomicAdd(&bh_e[t], he[t]);
    if (t < NB_NB && hn[t]) atomicAdd(&bh_n[t], hn[t]);
}

__global__ __launch_bounds__(256) void bscan(const int* __restrict__ bh_e,
                                             const int* __restrict__ bh_n,
                                             int* __restrict__ boff_e,
                                             int* __restrict__ boff_n,
                                             int* __restrict__ bcur_e,
                                             int* __restrict__ bcur_n,
                                             int* __restrict__ off_e,
                                             int* __restrict__ off_n) {
    __shared__ int ss[256];
    int t = threadIdx.x;
    int v = (t < NB_EB) ? bh_e[t] : 0;
    ss[t] = v;
    __syncthreads();
    for (int off = 1; off < 256; off <<= 1) {
        int add = (t >= off) ? ss[t - off] : 0;
        __syncthreads();
        ss[t] += add;
        __syncthreads();
    }
    if (t < NB_EB) { boff_e[t] = ss[t] - v; bcur_e[t] = ss[t] - v; }
    if (t == NB_EB - 1) { boff_e[NB_EB] = ss[t]; off_e[N_EDGES] = ss[t]; }
    __syncthreads();
    int v2 = (t < NB_NB) ? bh_n[t] : 0;
    ss[t] = v2;
    __syncthreads();
    for (int off = 1; off < 256; off <<= 1) {
        int add = (t >= off) ? ss[t - off] : 0;
        __syncthreads();
        ss[t] += add;
        __syncthreads();
    }
    if (t < NB_NB) { boff_n[t] = ss[t] - v2; bcur_n[t] = ss[t] - v2; }
    if (t == NB_NB - 1) { boff_n[NB_NB] = ss[t]; off_n[N_NODES] = ss[t]; }
}

// pairs_e word: node<<8 | (e&255); pairs_n word: edge<<9 | (n&511)
__global__ __launch_bounds__(256) void part_a(const int* __restrict__ ni,
                                              const int* __restrict__ ei,
                                              int* __restrict__ bcur_e,
                                              int* __restrict__ bcur_n,
                                              int* __restrict__ pairs_e,
                                              int* __restrict__ pairs_n) {
    __shared__ int he[NB_EB], hn[NB_NB], be[NB_EB], bn[NB_NB];
    int t = threadIdx.x;
    if (t < NB_EB) he[t] = 0;
    if (t < NB_NB) hn[t] = 0;
    __syncthreads();
    int base = blockIdx.x * 4096;
    int se[16], sn[16];
#pragma unroll
    for (int j = 0; j < 16; j++) {
        int i = base + t + j * 256;
        if (i < N_INC) {
            se[j] = ei[i]; sn[j] = ni[i];
            atomicAdd(&he[se[j] >> 8], 1);
            atomicAdd(&hn[sn[j] >> 9], 1);
        } else { se[j] = -1; sn[j] = -1; }
    }
    __syncthreads();
    if (t < NB_EB) be[t] = atomicAdd(&bcur_e[t], he[t]);
    if (t < NB_NB) bn[t] = atomicAdd(&bcur_n[t], hn[t]);
    __syncthreads();
    if (t < NB_EB) he[t] = 0;
    if (t < NB_NB) hn[t] = 0;
    __syncthreads();
#pragma unroll
    for (int j = 0; j < 16; j++) {
        if (se[j] >= 0) {
            int b = se[j] >> 8;
            int p = be[b] + atomicAdd(&he[b], 1);
            pairs_e[p] = (sn[j] << 8) | (se[j] & 255);
            int b2 = sn[j] >> 9;
            int p2 = bn[b2] + atomicAdd(&hn[b2], 1);
            pairs_n[p2] = (se[j] << 9) | (sn[j] & 511);
        }
    }
}

__global__ __launch_bounds__(256) void part_b_e(const int* __restrict__ pairs_e,
                                                const int* __restrict__ boff_e,
                                                int* __restrict__ off_e,
                                                int* __restrict__ csr_e) {
    __shared__ int ss[256], cur[256];
    int b = blockIdx.x, t = threadIdx.x;
    int r0 = boff_e[b], r1 = boff_e[b + 1];
    cur[t] = 0;
    __syncthreads();
    for (int i = r0 + t; i < r1; i += 256) atomicAdd(&cur[pairs_e[i] & 255], 1);
    __syncthreads();
    int v = cur[t];
    ss[t] = v;
    __syncthreads();
    for (int off = 1; off < 256; off <<= 1) {
        int add = (t >= off) ? ss[t - off] : 0;
        __syncthreads();
        ss[t] += add;
        __syncthreads();
    }
    int my = r0 + ss[t] - v;
    int e_id = b * 256 + t;
    if (e_id < N_EDGES) off_e[e_id] = my;
    __syncthreads();
    cur[t] = my;
    __syncthreads();
    for (int i = r0 + t; i < r1; i += 256) {
        int u = pairs_e[i];
        int p = atomicAdd(&cur[u & 255], 1);
        csr_e[p] = u >> 8;
    }
}

__global__ __launch_bounds__(512) void part_b_n(const int* __restrict__ pairs_n,
                                                const int* __restrict__ boff_n,
                                                int* __restrict__ off_n,
                                                int* __restrict__ csr_n) {
    __shared__ int ss[512], cur[512];
    int b = blockIdx.x, t = threadIdx.x;
    int r0 = boff_n[b], r1 = boff_n[b + 1];
    cur[t] = 0;
    __syncthreads();
    for (int i = r0 + t; i < r1; i += 512) atomicAdd(&cur[pairs_n[i] & 511], 1);
    __syncthreads();
    int v = cur[t];
    ss[t] = v;
    __syncthreads();
    for (int off = 1; off < 512; off <<= 1) {
        int add = (t >= off) ? ss[t - off] : 0;
        __syncthreads();
        ss[t] += add;
        __syncthreads();
    }
    int my = r0 + ss[t] - v;
    int n_id = b * 512 + t;
    if (n_id < N_NODES) off_n[n_id] = my;
    __syncthreads();
    cur[t] = my;
    __syncthreads();
    for (int i = r0 + t; i < r1; i += 512) {
        int u = pairs_n[i];
        int p = atomicAdd(&cur[u & 511], 1);
        csr_n[p] = u >> 9;
    }
}

// ---------------- GEMM (bf16 MFMA, Wt in LDS), on EDGE rows (25000) ----------------

__global__ void wt_prep(const float* __restrict__ W, __bf16* __restrict__ Wt) {
    int i = blockIdx.x * blockDim.x + threadIdx.x; // 16384
    int k = i >> 7, j = i & 127;
    Wt[j * 128 + k] = (__bf16)W[i];
}

__global__ __launch_bounds__(256) void gemm2_bf16(const __bf16* __restrict__ X,
                                                  const __bf16* __restrict__ Wt,
                                                  __bf16* __restrict__ Y,
                                                  int nrows) {
    __shared__ __bf16 WtS[128 * WTS];
    int t = threadIdx.x;
    for (int i = t; i < 2048; i += 256) {
        int col = i >> 4, ch = i & 15;
        *(float4*)(WtS + col * WTS + ch * 8) = ((const float4*)Wt)[i];
    }
    __syncthreads();

    int wave = t >> 6;
    int lane = t & 63;
    int quad = lane >> 4;
    int lr = lane & 15;
    int m0 = blockIdx.x * 128 + wave * 32;

    f32x4 acc[2][8];
#pragma unroll
    for (int mt = 0; mt < 2; mt++)
#pragma unroll
        for (int c = 0; c < 8; c++) acc[mt][c] = (f32x4){0.f, 0.f, 0.f, 0.f};

    int r0 = m0 + lr;       if (r0 >= nrows) r0 = 0;
    int r1 = m0 + 16 + lr;  if (r1 >= nrows) r1 = 0;
    const __bf16* x0p = X + (size_t)r0 * D + quad * 8;
    const __bf16* x1p = X + (size_t)r1 * D + quad * 8;

#pragma unroll
    for (int kk = 0; kk < 4; kk++) {
        bf16x8 a0 = *(const bf16x8*)(x0p + kk * 32);
        bf16x8 a1 = *(const bf16x8*)(x1p + kk * 32);
#pragma unroll
        for (int c = 0; c < 8; c++) {
            bf16x8 b = *(const bf16x8*)(WtS + (c * 16 + lr) * WTS + kk * 32 + quad * 8);
            acc[0][c] = __builtin_amdgcn_mfma_f32_16x16x32_bf16(a0, b, acc[0][c], 0, 0, 0);
            acc[1][c] = __builtin_amdgcn_mfma_f32_16x16x32_bf16(a1, b, acc[1][c], 0, 0, 0);
        }
    }

#pragma unroll
    for (int mt = 0; mt < 2; mt++)
#pragma unroll
        for (int r = 0; r < 4; r++) {
            int row_out = m0 + mt * 16 + quad * 4 + r;
            if (row_out < nrows) {
#pragma unroll
                for (int c = 0; c < 8; c++)
                    Y[(size_t)row_out * D + c * 16 + lr] = (__bf16)acc[mt][c][r];
            }
        }
}

// ---------------- Gather phases (bf16 rows, fp32 accumulate) ----------------
// 16 lanes per segment x bf16x8 = 128 elements; 8 segments per 128-thread block.

__global__ __launch_bounds__(128) void edge_gather(const __bf16* __restrict__ XW,
                                                   const int* __restrict__ off_e,
                                                   const int* __restrict__ csr_e,
                                                   __bf16* __restrict__ ef) {
    int e = blockIdx.x * 8 + (threadIdx.x >> 4);
    int lane = threadIdx.x & 15;
    int s = off_e[e], tend = off_e[e + 1];
    float acc[8] = {0.f, 0.f, 0.f, 0.f, 0.f, 0.f, 0.f, 0.f};
    int j = s;
    for (; j + 8 <= tend; j += 8) {
        int n0 = csr_e[j],     n1 = csr_e[j + 1], n2 = csr_e[j + 2], n3 = csr_e[j + 3];
        int n4 = csr_e[j + 4], n5 = csr_e[j + 5], n6 = csr_e[j + 6], n7 = csr_e[j + 7];
        bf16x8 v0 = *(const bf16x8*)(XW + n0 * 128 + lane * 8);
        bf16x8 v1 = *(const bf16x8*)(XW + n1 * 128 + lane * 8);
        bf16x8 v2 = *(const bf16x8*)(XW + n2 * 128 + lane * 8);
        bf16x8 v3 = *(const bf16x8*)(XW + n3 * 128 + lane * 8);
        bf16x8 v4 = *(const bf16x8*)(XW + n4 * 128 + lane * 8);
        bf16x8 v5 = *(const bf16x8*)(XW + n5 * 128 + lane * 8);
        bf16x8 v6 = *(const bf16x8*)(XW + n6 * 128 + lane * 8);
        bf16x8 v7 = *(const bf16x8*)(XW + n7 * 128 + lane * 8);
#pragma unroll
        for (int k = 0; k < 8; k++)
            acc[k] += (((float)v0[k] + (float)v1[k]) + ((float)v2[k] + (float)v3[k]))
                    + (((float)v4[k] + (float)v5[k]) + ((float)v6[k] + (float)v7[k]));
    }
    for (; j + 4 <= tend; j += 4) {
        int n0 = csr_e[j], n1 = csr_e[j + 1], n2 = csr_e[j + 2], n3 = csr_e[j + 3];
        bf16x8 v0 = *(const bf16x8*)(XW + n0 * 128 + lane * 8);
        bf16x8 v1 = *(const bf16x8*)(XW + n1 * 128 + lane * 8);
        bf16x8 v2 = *(const bf16x8*)(XW + n2 * 128 + lane * 8);
        bf16x8 v3 = *(const bf16x8*)(XW + n3 * 128 + lane * 8);
#pragma unroll
        for (int k = 0; k < 8; k++)
            acc[k] += ((float)v0[k] + (float)v1[k]) + ((float)v2[k] + (float)v3[k]);
    }
    for (; j < tend; j++) {
        bf16x8 v = *(const bf16x8*)(XW + csr_e[j] * 128 + lane * 8);
#pragma unroll
        for (int k = 0; k < 8; k++) acc[k] += (float)v[k];
    }
    int cnt = tend - s;
    float binv = (cnt > 0) ? 1.0f / (float)cnt : 0.0f;
    bf16x8 r;
#pragma unroll
    for (int k = 0; k < 8; k++) r[k] = (__bf16)(acc[k] * binv);
    *(bf16x8*)(ef + e * 128 + lane * 8) = r;
}

// mode 0: relu, bf16 out to hb; mode 1: no relu, fp32 out to of
__global__ __launch_bounds__(128) void node_gather(const __bf16* __restrict__ ef,
                                                   const int* __restrict__ off_n,
                                                   const int* __restrict__ csr_n,
                                                   const float* __restrict__ bias,
                                                   __bf16* __restrict__ hb,
                                                   float* __restrict__ of,
                                                   int mode) {
    int n = blockIdx.x * 8 + (threadIdx.x >> 4);
    int lane = threadIdx.x & 15;
    int s = off_n[n], tend = off_n[n + 1];
    float acc[8] = {0.f, 0.f, 0.f, 0.f, 0.f, 0.f, 0.f, 0.f};
    int j = s;
    for (; j + 4 <= tend; j += 4) {
        int e0 = csr_n[j], e1 = csr_n[j + 1], e2 = csr_n[j + 2], e3 = csr_n[j + 3];
        bf16x8 v0 = *(const bf16x8*)(ef + e0 * 128 + lane * 8);
        bf16x8 v1 = *(const bf16x8*)(ef + e1 * 128 + lane * 8);
        bf16x8 v2 = *(const bf16x8*)(ef + e2 * 128 + lane * 8);
        bf16x8 v3 = *(const bf16x8*)(ef + e3 * 128 + lane * 8);
#pragma unroll
        for (int k = 0; k < 8; k++)
            acc[k] += ((float)v0[k] + (float)v1[k]) + ((float)v2[k] + (float)v3[k]);
    }
    for (; j < tend; j++) {
        bf16x8 v = *(const bf16x8*)(ef + csr_n[j] * 128 + lane * 8);
#pragma unroll
        for (int k = 0; k < 8; k++) acc[k] += (float)v[k];
    }
    int cnt = tend - s;
    float dinv = (cnt > 0) ? 1.0f / (float)cnt : 0.0f;
    float4 b0 = ((const float4*)bias)[lane * 2];
    float4 b1 = ((const float4*)bias)[lane * 2 + 1];
    float vals[8];
    vals[0] = acc[0] * dinv + b0.x; vals[1] = acc[1] * dinv + b0.y;
    vals[2] = acc[2] * dinv + b0.z; vals[3] = acc[3] * dinv + b0.w;
    vals[4] = acc[4] * dinv + b1.x; vals[5] = acc[5] * dinv + b1.y;
    vals[6] = acc[6] * dinv + b1.z; vals[7] = acc[7] * dinv + b1.w;
    if (mode == 0) {
        bf16x8 r;
#pragma unroll
        for (int k = 0; k < 8; k++) r[k] = (__bf16)fmaxf(vals[k], 0.f);
        *(bf16x8*)(hb + n * 128 + lane * 8) = r;
    } else {
        float4 o0 = make_float4(vals[0], vals[1], vals[2], vals[3]);
        float4 o1 = make_float4(vals[4], vals[5], vals[6], vals[7]);
        ((float4*)of)[n * 32 + lane * 2] = o0;
        ((float4*)of)[n * 32 + lane * 2 + 1] = o1;
    }
}

// ---------------- launch ----------------

extern "C" void kernel_launch(void* const* d_in, const int* in_sizes, int n_in,
                              void* d_out, int out_size, void* d_ws, size_t ws_size,
                              hipStream_t stream) {
    const float* x        = (const float*)d_in[0];
    const int* node_idx   = (const int*)d_in[1];
    const int* edge_idx   = (const int*)d_in[2];
    const float* attr     = (const float*)d_in[3];
    const float* Wl[3]    = {(const float*)d_in[4], (const float*)d_in[6], (const float*)d_in[8]};
    const float* bl[3]    = {(const float*)d_in[5], (const float*)d_in[7], (const float*)d_in[9]};
    float* out = (float*)d_out;

    char* ws = (char*)d_ws;
    __bf16* Xb  = (__bf16*)ws;                  // [0 .. 25,600,000)
    __bf16* Hb  = (__bf16*)(ws + 25600000);     // [25,600,000 .. 51,200,000)
    __bf16* EFx = (__bf16*)(ws + 51200000);     // [51,200,000 .. 57,600,000)
    __bf16* EFy = (__bf16*)(ws + 57600000);     // [57,600,000 .. 64,000,000)
    int* csr_e = (int*)(ws + 64000000);         // 2,400,000 B -> 66,400,000
    int* csr_n = (int*)(ws + 66400000);         // 2,400,000 B -> 68,800,000
    int* off_e = (int*)(ws + 68800000);         // 100,004 B
    int* off_n = (int*)(ws + 68950000);         // 400,004 B -> 69,350,004
    int* ib    = (int*)(ws + 69400000);         // small int arrays
    int* bh_e   = ib;            // 98
    int* bh_n   = ib + 98;       // 196
    int* boff_e = ib + 294;      // 99
    int* boff_n = ib + 393;      // 197
    int* bcur_e = ib + 590;      // 98
    int* bcur_n = ib + 688;      // 196
    __bf16* Wt = (__bf16*)(ws + 69450000);      // 32,768 B -> ends 69,482,768
    // packed pairs live in Hb's region during CSR build (Hb first written in layer-0 node_gather)
    int* pairs_e = (int*)(ws + 25600000);       // 2,400,000 B
    int* pairs_n = (int*)(ws + 28000000);       // 2,400,000 B

    hipMemsetAsync(bh_e, 0, 294 * sizeof(int), stream);

    to_bf16<<<(N_NODES * D / 8 + 255) / 256, 256, 0, stream>>>(x, Xb, N_NODES * D / 8);
    bhist<<<NCHUNK, 256, 0, stream>>>(node_idx, edge_idx, bh_e, bh_n);
    bscan<<<1, 256, 0, stream>>>(bh_e, bh_n, boff_e, boff_n, bcur_e, bcur_n, off_e, off_n);
    part_a<<<NCHUNK, 256, 0, stream>>>(node_idx, edge_idx, bcur_e, bcur_n, pairs_e, pairs_n);
    part_b_e<<<NB_EB, 256, 0, stream>>>(pairs_e, boff_e, off_e, csr_e);
    part_b_n<<<NB_NB, 512, 0, stream>>>(pairs_n, boff_n, off_n, csr_n);

    for (int l = 0; l < 3; l++) {
        wt_prep<<<64, 256, 0, stream>>>(Wl[l], Wt);
        // edge aggregation first (linearity: D^-1 H B H^T (XW) = D^-1 H B ((H^T X) W))
        edge_gather<<<N_EDGES / 8, 128, 0, stream>>>(l == 0 ? Xb : Hb, off_e, csr_e, EFx);
        gemm2_bf16<<<(N_EDGES + 127) / 128, 256, 0, stream>>>(EFx, Wt, EFy, N_EDGES);
        node_gather<<<N_NODES / 8, 128, 0, stream>>>(EFy, off_n, csr_n, bl[l],
                                                     Hb, out, (l < 2) ? 0 : 1);
    }

    hipMemcpyAsync(out + N_NODES * D, attr, N_EDGES * 32 * sizeof(float),
                   hipMemcpyDeviceToDevice, stream);
}

// Round 8
// 328.052 us; speedup vs baseline: 2.7705x; 1.0713x over previous
//
#include <hip/hip_runtime.h>

#define N_NODES 100000
#define N_EDGES 25000
#define N_INC   600000
#define D       128
#define NB_EB   98     // edge buckets: 256 edges each (e>>8)
#define NB_NB   196    // node buckets: 512 nodes each (n>>9)
#define CAP_EB  8192   // slab capacity per edge bucket (mean 6122, +26 sigma)
#define CAP_NB  4096   // slab capacity per node bucket (mean 3061, +21 sigma)
#define NCHUNK  147    // ceil(600000/4096)
#define WTS     136    // LDS stride for Wt: conflict-free b128 reads

typedef __bf16 bf16x8 __attribute__((ext_vector_type(8)));
typedef float  f32x4  __attribute__((ext_vector_type(4)));

// ---------------- fp32 -> bf16 cast (x only, once) ----------------

__global__ __launch_bounds__(256) void to_bf16(const float* __restrict__ X,
                                               __bf16* __restrict__ Y, int n8) {
    int i = blockIdx.x * blockDim.x + threadIdx.x;
    if (i < n8) {
        float4 a = ((const float4*)X)[i * 2];
        float4 b = ((const float4*)X)[i * 2 + 1];
        bf16x8 r;
        r[0] = (__bf16)a.x; r[1] = (__bf16)a.y; r[2] = (__bf16)a.z; r[3] = (__bf16)a.w;
        r[4] = (__bf16)b.x; r[5] = (__bf16)b.y; r[6] = (__bf16)b.z; r[7] = (__bf16)b.w;
        *(bf16x8*)(Y + i * 8) = r;
    }
}

// ---------------- CSR build: strided bucket slabs (no pre-histogram) ----------------
// pairs_e word: node<<8 | (e&255); pairs_n word: edge<<9 | (n&511)

__global__ __launch_bounds__(256) void part_a(const int* __restrict__ ni,
                                              const int* __restrict__ ei,
                                              int* __restrict__ bcur_e,
                                              int* __restrict__ bcur_n,
                                              int* __restrict__ pairs_e,
                                              int* __restrict__ pairs_n) {
    __shared__ int he[NB_EB], hn[NB_NB], be[NB_EB], bn[NB_NB];
    int t = threadIdx.x;
    if (t < NB_EB) he[t] = 0;
    if (t < NB_NB) hn[t] = 0;
    __syncthreads();
    int base = blockIdx.x * 4096;
    int se[16], sn[16];
#pragma unroll
    for (int j = 0; j < 16; j++) {
        int i = base + t + j * 256;
        if (i < N_INC) {
            se[j] = ei[i]; sn[j] = ni[i];
            atomicAdd(&he[se[j] >> 8], 1);
            atomicAdd(&hn[sn[j] >> 9], 1);
        } else { se[j] = -1; sn[j] = -1; }
    }
    __syncthreads();
    if (t < NB_EB) be[t] = t * CAP_EB + atomicAdd(&bcur_e[t], he[t]);
    if (t < NB_NB) bn[t] = t * CAP_NB + atomicAdd(&bcur_n[t], hn[t]);
    __syncthreads();
    if (t < NB_EB) he[t] = 0;
    if (t < NB_NB) hn[t] = 0;
    __syncthreads();
#pragma unroll
    for (int j = 0; j < 16; j++) {
        if (se[j] >= 0) {
            int b = se[j] >> 8;
            int p = be[b] + atomicAdd(&he[b], 1);
            pairs_e[p] = (sn[j] << 8) | (se[j] & 255);
            int b2 = sn[j] >> 9;
            int p2 = bn[b2] + atomicAdd(&hn[b2], 1);
            pairs_n[p2] = (se[j] << 9) | (sn[j] & 511);
        }
    }
}

// Exclusive scan of final bucket counts -> dense bucket bases + CSR sentinels.
__global__ __launch_bounds__(256) void bscan2(const int* __restrict__ bcur_e,
                                              const int* __restrict__ bcur_n,
                                              int* __restrict__ boff_e,
                                              int* __restrict__ boff_n,
                                              int* __restrict__ off_e,
                                              int* __restrict__ off_n) {
    __shared__ int ss[256];
    int t = threadIdx.x;
    int v = (t < NB_EB) ? bcur_e[t] : 0;
    ss[t] = v;
    __syncthreads();
    for (int off = 1; off < 256; off <<= 1) {
        int add = (t >= off) ? ss[t - off] : 0;
        __syncthreads();
        ss[t] += add;
        __syncthreads();
    }
    if (t < NB_EB) boff_e[t] = ss[t] - v;
    if (t == NB_EB - 1) { boff_e[NB_EB] = ss[t]; off_e[N_EDGES] = ss[t]; }
    __syncthreads();
    int v2 = (t < NB_NB) ? bcur_n[t] : 0;
    ss[t] = v2;
    __syncthreads();
    for (int off = 1; off < 256; off <<= 1) {
        int add = (t >= off) ? ss[t - off] : 0;
        __syncthreads();
        ss[t] += add;
        __syncthreads();
    }
    if (t < NB_NB) boff_n[t] = ss[t] - v2;
    if (t == NB_NB - 1) { boff_n[NB_NB] = ss[t]; off_n[N_NODES] = ss[t]; }
}

__global__ __launch_bounds__(256) void part_b_e(const int* __restrict__ pairs_e,
                                                const int* __restrict__ bcnt_e,
                                                const int* __restrict__ boff_e,
                                                int* __restrict__ off_e,
                                                int* __restrict__ csr_e) {
    __shared__ int ss[256], cur[256];
    int b = blockIdx.x, t = threadIdx.x;
    int r0 = b * CAP_EB, r1 = r0 + bcnt_e[b];
    int ob = boff_e[b];
    cur[t] = 0;
    __syncthreads();
    for (int i = r0 + t; i < r1; i += 256) atomicAdd(&cur[pairs_e[i] & 255], 1);
    __syncthreads();
    int v = cur[t];
    ss[t] = v;
    __syncthreads();
    for (int off = 1; off < 256; off <<= 1) {
        int add = (t >= off) ? ss[t - off] : 0;
        __syncthreads();
        ss[t] += add;
        __syncthreads();
    }
    int my = ob + ss[t] - v;
    int e_id = b * 256 + t;
    if (e_id < N_EDGES) off_e[e_id] = my;
    __syncthreads();
    cur[t] = my;
    __syncthreads();
    for (int i = r0 + t; i < r1; i += 256) {
        int u = pairs_e[i];
        int p = atomicAdd(&cur[u & 255], 1);
        csr_e[p] = u >> 8;
    }
}

__global__ __launch_bounds__(512) void part_b_n(const int* __restrict__ pairs_n,
                                                const int* __restrict__ bcnt_n,
                                                const int* __restrict__ boff_n,
                                                int* __restrict__ off_n,
                                                int* __restrict__ csr_n) {
    __shared__ int ss[512], cur[512];
    int b = blockIdx.x, t = threadIdx.x;
    int r0 = b * CAP_NB, r1 = r0 + bcnt_n[b];
    int ob = boff_n[b];
    cur[t] = 0;
    __syncthreads();
    for (int i = r0 + t; i < r1; i += 512) atomicAdd(&cur[pairs_n[i] & 511], 1);
    __syncthreads();
    int v = cur[t];
    ss[t] = v;
    __syncthreads();
    for (int off = 1; off < 512; off <<= 1) {
        int add = (t >= off) ? ss[t - off] : 0;
        __syncthreads();
        ss[t] += add;
        __syncthreads();
    }
    int my = ob + ss[t] - v;
    int n_id = b * 512 + t;
    if (n_id < N_NODES) off_n[n_id] = my;
    __syncthreads();
    cur[t] = my;
    __syncthreads();
    for (int i = r0 + t; i < r1; i += 512) {
        int u = pairs_n[i];
        int p = atomicAdd(&cur[u & 511], 1);
        csr_n[p] = u >> 9;
    }
}

// ---------------- Wt prep: all 3 layers in one launch ----------------

__global__ void wt_prep_all(const float* __restrict__ W0,
                            const float* __restrict__ W1,
                            const float* __restrict__ W2,
                            __bf16* __restrict__ Wt) {
    int l = blockIdx.x >> 6;
    int i = (blockIdx.x & 63) * 256 + threadIdx.x;   // 0..16383
    const float* W = (l == 0) ? W0 : (l == 1) ? W1 : W2;
    int k = i >> 7, j = i & 127;
    Wt[l * 16384 + j * 128 + k] = (__bf16)W[i];
}

// ---------------- GEMM (bf16 MFMA, Wt in LDS), on EDGE rows ----------------

__global__ __launch_bounds__(256) void gemm2_bf16(const __bf16* __restrict__ X,
                                                  const __bf16* __restrict__ Wt,
                                                  __bf16* __restrict__ Y,
                                                  int nrows) {
    __shared__ __bf16 WtS[128 * WTS];
    int t = threadIdx.x;
    for (int i = t; i < 2048; i += 256) {
        int col = i >> 4, ch = i & 15;
        *(float4*)(WtS + col * WTS + ch * 8) = ((const float4*)Wt)[i];
    }
    __syncthreads();

    int wave = t >> 6;
    int lane = t & 63;
    int quad = lane >> 4;
    int lr = lane & 15;
    int m0 = blockIdx.x * 128 + wave * 32;

    f32x4 acc[2][8];
#pragma unroll
    for (int mt = 0; mt < 2; mt++)
#pragma unroll
        for (int c = 0; c < 8; c++) acc[mt][c] = (f32x4){0.f, 0.f, 0.f, 0.f};

    int r0 = m0 + lr;       if (r0 >= nrows) r0 = 0;
    int r1 = m0 + 16 + lr;  if (r1 >= nrows) r1 = 0;
    const __bf16* x0p = X + (size_t)r0 * D + quad * 8;
    const __bf16* x1p = X + (size_t)r1 * D + quad * 8;

#pragma unroll
    for (int kk = 0; kk < 4; kk++) {
        bf16x8 a0 = *(const bf16x8*)(x0p + kk * 32);
        bf16x8 a1 = *(const bf16x8*)(x1p + kk * 32);
#pragma unroll
        for (int c = 0; c < 8; c++) {
            bf16x8 b = *(const bf16x8*)(WtS + (c * 16 + lr) * WTS + kk * 32 + quad * 8);
            acc[0][c] = __builtin_amdgcn_mfma_f32_16x16x32_bf16(a0, b, acc[0][c], 0, 0, 0);
            acc[1][c] = __builtin_amdgcn_mfma_f32_16x16x32_bf16(a1, b, acc[1][c], 0, 0, 0);
        }
    }

#pragma unroll
    for (int mt = 0; mt < 2; mt++)
#pragma unroll
        for (int r = 0; r < 4; r++) {
            int row_out = m0 + mt * 16 + quad * 4 + r;
            if (row_out < nrows) {
#pragma unroll
                for (int c = 0; c < 8; c++)
                    Y[(size_t)row_out * D + c * 16 + lr] = (__bf16)acc[mt][c][r];
            }
        }
}

// ---------------- Gather phases: masked 8-wide, no serial tail ----------------
// 16 lanes per segment x bf16x8 = 128 elements; 8 segments per 128-thread block.

__global__ __launch_bounds__(128) void edge_gather(const __bf16* __restrict__ XW,
                                                   const int* __restrict__ off_e,
                                                   const int* __restrict__ csr_e,
                                                   __bf16* __restrict__ ef) {
    int e = blockIdx.x * 8 + (threadIdx.x >> 4);
    int lane = threadIdx.x & 15;
    int s = off_e[e], tend = off_e[e + 1];
    float acc[8] = {0.f, 0.f, 0.f, 0.f, 0.f, 0.f, 0.f, 0.f};
    for (int j = s; j < tend; j += 8) {
        int idx[8]; float m[8];
#pragma unroll
        for (int k = 0; k < 8; k++) {
            int jj = j + k;
            bool ok = jj < tend;
            idx[k] = csr_e[ok ? jj : tend - 1];
            m[k] = ok ? 1.0f : 0.0f;
        }
        bf16x8 v[8];
#pragma unroll
        for (int k = 0; k < 8; k++)
            v[k] = *(const bf16x8*)(XW + (size_t)idx[k] * 128 + lane * 8);
#pragma unroll
        for (int k = 0; k < 8; k++)
#pragma unroll
            for (int q = 0; q < 8; q++)
                acc[q] = fmaf(m[k], (float)v[k][q], acc[q]);
    }
    int cnt = tend - s;
    float binv = (cnt > 0) ? 1.0f / (float)cnt : 0.0f;
    bf16x8 r;
#pragma unroll
    for (int k = 0; k < 8; k++) r[k] = (__bf16)(acc[k] * binv);
    *(bf16x8*)(ef + e * 128 + lane * 8) = r;
}

// mode 0: relu, bf16 out to hb; mode 1: no relu, fp32 out to of
__global__ __launch_bounds__(128) void node_gather(const __bf16* __restrict__ ef,
                                                   const int* __restrict__ off_n,
                                                   const int* __restrict__ csr_n,
                                                   const float* __restrict__ bias,
                                                   __bf16* __restrict__ hb,
                                                   float* __restrict__ of,
                                                   int mode) {
    int n = blockIdx.x * 8 + (threadIdx.x >> 4);
    int lane = threadIdx.x & 15;
    int s = off_n[n], tend = off_n[n + 1];
    float acc[8] = {0.f, 0.f, 0.f, 0.f, 0.f, 0.f, 0.f, 0.f};
    for (int j = s; j < tend; j += 8) {
        int idx[8]; float m[8];
#pragma unroll
        for (int k = 0; k < 8; k++) {
            int jj = j + k;
            bool ok = jj < tend;
            idx[k] = csr_n[ok ? jj : tend - 1];
            m[k] = ok ? 1.0f : 0.0f;
        }
        bf16x8 v[8];
#pragma unroll
        for (int k = 0; k < 8; k++)
            v[k] = *(const bf16x8*)(ef + (size_t)idx[k] * 128 + lane * 8);
#pragma unroll
        for (int k = 0; k < 8; k++)
#pragma unroll
            for (int q = 0; q < 8; q++)
                acc[q] = fmaf(m[k], (float)v[k][q], acc[q]);
    }
    int cnt = tend - s;
    float dinv = (cnt > 0) ? 1.0f / (float)cnt : 0.0f;
    float4 b0 = ((const float4*)bias)[lane * 2];
    float4 b1 = ((const float4*)bias)[lane * 2 + 1];
    float vals[8];
    vals[0] = acc[0] * dinv + b0.x; vals[1] = acc[1] * dinv + b0.y;
    vals[2] = acc[2] * dinv + b0.z; vals[3] = acc[3] * dinv + b0.w;
    vals[4] = acc[4] * dinv + b1.x; vals[5] = acc[5] * dinv + b1.y;
    vals[6] = acc[6] * dinv + b1.z; vals[7] = acc[7] * dinv + b1.w;
    if (mode == 0) {
        bf16x8 r;
#pragma unroll
        for (int k = 0; k < 8; k++) r[k] = (__bf16)fmaxf(vals[k], 0.f);
        *(bf16x8*)(hb + n * 128 + lane * 8) = r;
    } else {
        float4 o0 = make_float4(vals[0], vals[1], vals[2], vals[3]);
        float4 o1 = make_float4(vals[4], vals[5], vals[6], vals[7]);
        ((float4*)of)[n * 32 + lane * 2] = o0;
        ((float4*)of)[n * 32 + lane * 2 + 1] = o1;
    }
}

// ---------------- launch ----------------

extern "C" void kernel_launch(void* const* d_in, const int* in_sizes, int n_in,
                              void* d_out, int out_size, void* d_ws, size_t ws_size,
                              hipStream_t stream) {
    const float* x        = (const float*)d_in[0];
    const int* node_idx   = (const int*)d_in[1];
    const int* edge_idx   = (const int*)d_in[2];
    const float* attr     = (const float*)d_in[3];
    const float* Wl[3]    = {(const float*)d_in[4], (const float*)d_in[6], (const float*)d_in[8]};
    const float* bl[3]    = {(const float*)d_in[5], (const float*)d_in[7], (const float*)d_in[9]};
    float* out = (float*)d_out;

    char* ws = (char*)d_ws;
    __bf16* Xb  = (__bf16*)ws;                  // [0 .. 25,600,000)
    __bf16* Hb  = (__bf16*)(ws + 25600000);     // [25,600,000 .. 51,200,000)
    __bf16* EFx = (__bf16*)(ws + 51200000);     // [51,200,000 .. 57,600,000)
    __bf16* EFy = (__bf16*)(ws + 57600000);     // [57,600,000 .. 64,000,000)
    int* csr_e = (int*)(ws + 64000000);         // 2,400,000 B -> 66,400,000
    int* csr_n = (int*)(ws + 66400000);         // 2,400,000 B -> 68,800,000
    int* off_e = (int*)(ws + 68800000);         // 100,004 B
    int* off_n = (int*)(ws + 68950000);         // 400,004 B -> 69,350,004
    int* ib    = (int*)(ws + 69400000);         // bcur_e(98), bcur_n(196), boff_e(99), boff_n(197)
    int* bcur_e = ib;
    int* bcur_n = ib + 98;
    int* boff_e = ib + 294;
    int* boff_n = ib + 393;
    __bf16* Wt3 = (__bf16*)(ws + 69450000);     // 3 x 32,768 B -> ends 69,548,304
    // strided pair slabs live in Hb region during CSR build (Hb first written in layer-0 node_gather)
    int* pairs_e = (int*)(ws + 25600000);       // 98*8192*4  = 3,211,264 B -> ends 28,811,264
    int* pairs_n = (int*)(ws + 28900000);       // 196*4096*4 = 3,211,264 B -> ends 32,111,264

    hipMemsetAsync(bcur_e, 0, 294 * sizeof(int), stream);

    to_bf16<<<(N_NODES * D / 8 + 255) / 256, 256, 0, stream>>>(x, Xb, N_NODES * D / 8);
    part_a<<<NCHUNK, 256, 0, stream>>>(node_idx, edge_idx, bcur_e, bcur_n, pairs_e, pairs_n);
    bscan2<<<1, 256, 0, stream>>>(bcur_e, bcur_n, boff_e, boff_n, off_e, off_n);
    part_b_e<<<NB_EB, 256, 0, stream>>>(pairs_e, bcur_e, boff_e, off_e, csr_e);
    part_b_n<<<NB_NB, 512, 0, stream>>>(pairs_n, bcur_n, boff_n, off_n, csr_n);
    wt_prep_all<<<192, 256, 0, stream>>>(Wl[0], Wl[1], Wl[2], Wt3);

    for (int l = 0; l < 3; l++) {
        // linearity: D^-1 H B H^T (XW) = D^-1 H B ((H^T X) W)
        edge_gather<<<N_EDGES / 8, 128, 0, stream>>>(l == 0 ? Xb : Hb, off_e, csr_e, EFx);
        gemm2_bf16<<<(N_EDGES + 127) / 128, 256, 0, stream>>>(EFx, Wt3 + l * 16384, EFy, N_EDGES);
        node_gather<<<N_NODES / 8, 128, 0, stream>>>(EFy, off_n, csr_n, bl[l],
                                                     Hb, out, (l < 2) ? 0 : 1);
    }

    hipMemcpyAsync(out + N_NODES * D, attr, N_EDGES * 32 * sizeof(float),
                   hipMemcpyDeviceToDevice, stream);
}